// Round 1
// 7630.066 us; speedup vs baseline: 1.8537x; 1.8537x over previous
//
#include <hip/hip_runtime.h>

// WindowedMultiHeadAttention. B=16, 56x56 tokens, C=768, 8 heads x d=96,
// 14x14 windows -> 256 windows x 196 tokens.
// Round 3: K1 (KV GEMM) and K3 (proj GEMM) rewritten on MFMA bf16
// (v_mfma_f32_16x16x32_bf16, 128x128 tile, BK=32, 4 waves of 64x64, LDS
// rows padded to 40 bf16 = 80B stride -> 2-way bank aliasing, 16B aligned).
// qattn (K2) unchanged this round — it is the next target.
//   K1<FP32>: kb/vb = win_part(x) @ w_qkv[k,v cols] + bias   (MFMA)
//   K2<FP32>: per-(window,head) q-tile GEMM + softmax attention (scalar)
//   K3<FP32>: proj GEMM + bias + window reverse + residual    (MFMA)
// ws: kb 77,070,336 B | vb/attn_out 77,070,336 B | flag 4 B  (154,140,676 B)

#define NWIN 256
#define NTOK 196
#define CDIM 768
#define NHEAD 8
#define DHEAD 96
#define C3 2304

typedef unsigned short u16;
typedef unsigned int u32;
typedef __attribute__((ext_vector_type(8))) short bf16x8;  // 8 bf16 (4 VGPRs)
typedef __attribute__((ext_vector_type(4))) float f32x4;   // MFMA C/D frag

__device__ __forceinline__ float bf2f(u16 u) {
    union { u32 i; float f; } cv;
    cv.i = ((u32)u) << 16;
    return cv.f;
}
__device__ __forceinline__ float2 bfp2f(u32 u) {
    union { u32 i; float f; } lo, hi;
    lo.i = u << 16;
    hi.i = u & 0xFFFF0000u;
    float2 r; r.x = lo.f; r.y = hi.f;
    return r;
}
__device__ __forceinline__ u16 f2bf(float f) {
    union { float f; u32 i; } cv;
    cv.f = f;
    u32 x = cv.i;
    x = x + 0x7FFFu + ((x >> 16) & 1u);   // RNE
    return (u16)(x >> 16);
}
__device__ __forceinline__ u32 pack2bf(float a, float b) {
    return (u32)f2bf(a) | ((u32)f2bf(b) << 16);
}

// ------------------------------------------------------------- dtype detect
// flag=1 -> inputs are fp32; flag=0 -> bf16.
__global__ void detect_kernel(const u16* __restrict__ w, int* __restrict__ flag) {
    __shared__ int any;
    int t = threadIdx.x;
    if (t == 0) any = 0;
    __syncthreads();
    int hit = 0;
    for (int i = 0; i < 16; ++i) {
        u16 u = w[t * 16 + i];
        int e = (u >> 7) & 0xFF;
        if (e >= 140) hit = 1;    // |val| >= 2^13: impossible for bf16 weights
    }
    if (hit) atomicOr(&any, 1);
    __syncthreads();
    if (t == 0) flag[0] = any;
}

// ---------------------------------------------------------- K1: KV GEMM, MFMA
// C(50176 x 1536) = Xwin(50176 x 768) @ Wkv(768 x 1536, gathered cols).
// Block tile 128x128: cols 0..63 = K at d in [nb*64, nb*64+64),
//                     cols 64..127 = V at same d range (source cols adjacent:
//                     h*288+3d+1 / +2 -> gather loads pair up).
// 4 waves (2x2), each 64x64 = 4x4 frags of 16x16x32. Exact fit: M=392*128,
// K=24*32, N(d)=12*64 — no edge cases.
template<bool FP32>
__global__ __launch_bounds__(256, 2) void kvmm_kernel(
    const void* __restrict__ xv, const void* __restrict__ wqv,
    const void* __restrict__ bvv, const int* __restrict__ flag,
    u16* __restrict__ kb, u16* __restrict__ vb)
{
    if (flag[0] != (FP32 ? 1 : 0)) return;
    __shared__ u16 As[128 * 40];   // A[row][k], 40-pad (80B stride)
    __shared__ u16 Bs[128 * 40];   // Bt[c][k] (col-major W tile)

    int t = threadIdx.x;
    int mb = blockIdx.x % 392;
    int nb = blockIdx.x / 392;

    // ---- A staging coords: thread = (row, 16-col half) ----
    int arow = t >> 1, ahalf = t & 1;
    {
    }
    int r = mb * 128 + arow;
    int wi = r / 196, tok = r - wi * 196;
    int b_ = wi >> 4, wrem = wi & 15, wr = wrem >> 2, wc = wrem & 3;
    int tr = tok / 14, tc = tok - tr * 14;
    size_t xrow = ((size_t)b_ * 3136 + (size_t)((wr * 14 + tr) * 56 + wc * 14 + tc)) * CDIM;

    // ---- B staging coords: thread = (k-pair kp, 4 d-cols dg*4..+3) ----
    int kp = t >> 4;      // k rows 2kp, 2kp+1
    int dg = t & 15;
    int scol[4];
#pragma unroll
    for (int i = 0; i < 4; ++i) {
        int d_abs = nb * 64 + dg * 4 + i;
        int h = d_abs / 96, dh = d_abs - h * 96;
        scol[i] = h * 288 + 3 * dh + 1;   // K col; V col = scol+1
    }

    f32x4 acc[4][4];
#pragma unroll
    for (int m = 0; m < 4; ++m)
#pragma unroll
        for (int n = 0; n < 4; ++n)
            acc[m][n] = (f32x4){0.f, 0.f, 0.f, 0.f};

    int lane = t & 63, wvid = t >> 6;
    int wm = wvid >> 1, wn = wvid & 1;
    int lo = lane & 15, hi = lane >> 4;

#pragma unroll 1
    for (int kk = 0; kk < 24; ++kk) {
        int k0 = kk * 32;
        // ---- stage A (x -> bf16) ----
        {
            u32* dst = (u32*)&As[arow * 40 + ahalf * 16];
            if (FP32) {
                const float4* xp = (const float4*)((const float*)xv + xrow + k0 + ahalf * 16);
                float4 f0 = xp[0], f1 = xp[1], f2 = xp[2], f3 = xp[3];
                dst[0] = pack2bf(f0.x, f0.y); dst[1] = pack2bf(f0.z, f0.w);
                dst[2] = pack2bf(f1.x, f1.y); dst[3] = pack2bf(f1.z, f1.w);
                dst[4] = pack2bf(f2.x, f2.y); dst[5] = pack2bf(f2.z, f2.w);
                dst[6] = pack2bf(f3.x, f3.y); dst[7] = pack2bf(f3.z, f3.w);
            } else {
                const uint4* xp = (const uint4*)((const u16*)xv + xrow + k0 + ahalf * 16);
                uint4 q0 = xp[0], q1 = xp[1];
                ((uint4*)dst)[0] = q0;
                ((uint4*)dst)[1] = q1;
            }
        }
        // ---- stage B (w gather, transposed: Bt[c][k]) ----
        if (FP32) {
            const float* w0p = (const float*)wqv + (size_t)(k0 + 2 * kp) * C3;
            const float* w1p = w0p + C3;
#pragma unroll
            for (int i = 0; i < 4; ++i) {
                int c = dg * 4 + i;
                float ka0 = w0p[scol[i]],     ka1 = w1p[scol[i]];
                float va0 = w0p[scol[i] + 1], va1 = w1p[scol[i] + 1];
                *(u32*)&Bs[(c)      * 40 + 2 * kp] = pack2bf(ka0, ka1);
                *(u32*)&Bs[(64 + c) * 40 + 2 * kp] = pack2bf(va0, va1);
            }
        } else {
            const u16* w0p = (const u16*)wqv + (size_t)(k0 + 2 * kp) * C3;
            const u16* w1p = w0p + C3;
#pragma unroll
            for (int i = 0; i < 4; ++i) {
                int c = dg * 4 + i;
                u32 ka0 = w0p[scol[i]],     ka1 = w1p[scol[i]];
                u32 va0 = w0p[scol[i] + 1], va1 = w1p[scol[i] + 1];
                *(u32*)&Bs[(c)      * 40 + 2 * kp] = ka0 | (ka1 << 16);
                *(u32*)&Bs[(64 + c) * 40 + 2 * kp] = va0 | (va1 << 16);
            }
        }
        __syncthreads();
        // ---- fragments + MFMA ----
        // A frag: lane holds A[row=lo][k=hi*8+j];  B frag: B[k=hi*8+j][col=lo]
        bf16x8 af[4], bfr[4];
#pragma unroll
        for (int m = 0; m < 4; ++m)
            af[m] = *(const bf16x8*)&As[(wm * 64 + m * 16 + lo) * 40 + hi * 8];
#pragma unroll
        for (int n = 0; n < 4; ++n)
            bfr[n] = *(const bf16x8*)&Bs[(wn * 64 + n * 16 + lo) * 40 + hi * 8];
#pragma unroll
        for (int m = 0; m < 4; ++m)
#pragma unroll
            for (int n = 0; n < 4; ++n)
                acc[m][n] = __builtin_amdgcn_mfma_f32_16x16x32_bf16(af[m], bfr[n], acc[m][n], 0, 0, 0);
        __syncthreads();
    }

    // ---- store (+bias). D frag: col = lo, row = hi*4 + j ----
    u16* obuf = wn ? vb : kb;
    float bias[4];
    int h_[4], dh_[4];
#pragma unroll
    for (int n = 0; n < 4; ++n) {
        int d_abs = nb * 64 + n * 16 + lo;
        h_[n] = d_abs / 96; dh_[n] = d_abs - h_[n] * 96;
        int bcol = h_[n] * 288 + 3 * dh_[n] + (wn ? 2 : 1);
        bias[n] = FP32 ? ((const float*)bvv)[bcol] : bf2f(((const u16*)bvv)[bcol]);
    }
#pragma unroll
    for (int m = 0; m < 4; ++m) {
#pragma unroll
        for (int j = 0; j < 4; ++j) {
            int rr = mb * 128 + wm * 64 + m * 16 + hi * 4 + j;
            int wi2 = rr / 196, tk = rr - wi2 * 196;
            size_t rowpart = (size_t)wi2 * (8 * 196) + (size_t)tk;
#pragma unroll
            for (int n = 0; n < 4; ++n) {
                size_t dst = (rowpart + (size_t)h_[n] * 196) * 96 + dh_[n];
                obuf[dst] = f2bf(acc[m][n][j] + bias[n]);
            }
        }
    }
}

// ------------------------------------------------- K2: q-tile GEMM + attention
// block = (window, head); thread t = query row t (t<196 active).
// Phase A: q[96] = x_window(row t) @ Wq_h + bias (LDS-staged tiles).
// Phase B: two-pass softmax attention vs global K,V (bf16), 49-key LDS chunks.
// Output overwrites this block's own V slice.
__device__ __forceinline__ float dot96(const u32* qpk, const float* kr) {
    float e = 0.f;
#pragma unroll
    for (int dp = 0; dp < 48; ++dp) {
        float2 qf = bfp2f(qpk[dp]);
        e = fmaf(qf.x, kr[2 * dp], e);
        e = fmaf(qf.y, kr[2 * dp + 1], e);
    }
    return e;
}

template<bool FP32>
__global__ __launch_bounds__(256) void qattn_kernel(
    const void* __restrict__ xv, const void* __restrict__ wv,
    const void* __restrict__ bvv, const int* __restrict__ flag,
    const u16* __restrict__ kb, u16* __restrict__ vb)
{
    if (flag[0] != (FP32 ? 1 : 0)) return;
    __shared__ float swq[32 * 96];        // 12,288 B  (Wq tile, fp32)
    __shared__ u32   sxq[196][17];        // 13,328 B  (x tile, packed bf16)
    __shared__ float sk[49 * DHEAD];      // 18,816 B
    __shared__ float sv[49 * DHEAD];      // 18,816 B   total 63,248 B

    int bh = blockIdx.x;                  // wi*8 + h
    int wi = bh >> 3;
    int h  = bh & 7;
    int t  = threadIdx.x;
    int rt = t < NTOK ? t : (NTOK - 1);

    int b = wi >> 4, wrem = wi & 15, wr = wrem >> 2, wc = wrem & 3;
    size_t xrowbase = (size_t)b * 3136 + (size_t)(wr * 14 * 56 + wc * 14);

    // ---------------- Phase A: q row for this thread ----------------
    float q[DHEAD];
#pragma unroll
    for (int d = 0; d < DHEAD; ++d) q[d] = 0.f;

#pragma unroll 1
    for (int k0 = 0; k0 < CDIM; k0 += 32) {
        // stage Wq tile: swq[kk][d] = w[(k0+kk)*2304 + h*288 + 3d]
#pragma unroll 1
        for (int i = t; i < 32 * 96; i += 256) {
            int kk = i / 96, d = i - kk * 96;
            size_t idx = (size_t)(k0 + kk) * C3 + (size_t)(h * 288 + 3 * d);
            swq[i] = FP32 ? ((const float*)wv)[idx] : bf2f(((const u16*)wv)[idx]);
        }
        // stage x tile: sxq[tok][p] = packed bf16 pair (k0+2p, k0+2p+1)
#pragma unroll 1
        for (int i = t; i < 196 * 16; i += 256) {
            int tok = i >> 4, p = i & 15;
            int r = tok / 14, c = tok - r * 14;
            size_t e0 = (xrowbase + (size_t)(r * 56 + c)) * CDIM + (size_t)(k0 + 2 * p);
            u32 u;
            if (FP32) {
                float2 f = *(const float2*)((const float*)xv + e0);
                u = (u32)f2bf(f.x) | ((u32)f2bf(f.y) << 16);
            } else {
                u = *(const u32*)((const u16*)xv + e0);
            }
            sxq[tok][p] = u;
        }
        __syncthreads();
#pragma unroll 2
        for (int kk = 0; kk < 32; ++kk) {
            float2 xp = bfp2f(sxq[rt][kk >> 1]);
            float xs = (kk & 1) ? xp.y : xp.x;
            const float* wrow = &swq[kk * 96];
#pragma unroll
            for (int d = 0; d < DHEAD; ++d) q[d] = fmaf(xs, wrow[d], q[d]);
        }
        __syncthreads();
    }

    // bias + pack q to bf16 pairs
    u32 qpk[48];
#pragma unroll
    for (int dp = 0; dp < 48; ++dp) {
        int d0 = 2 * dp;
        float b0, b1;
        if (FP32) {
            b0 = ((const float*)bvv)[h * 288 + 3 * d0];
            b1 = ((const float*)bvv)[h * 288 + 3 * (d0 + 1)];
        } else {
            b0 = bf2f(((const u16*)bvv)[h * 288 + 3 * d0]);
            b1 = bf2f(((const u16*)bvv)[h * 288 + 3 * (d0 + 1)]);
        }
        qpk[dp] = (u32)f2bf(q[d0] + b0) | ((u32)f2bf(q[d0 + 1] + b1) << 16);
    }

    // ---------------- Phase B: attention ----------------
    const u16* kbase = kb + (size_t)bh * NTOK * DHEAD;
    u16*       vbase = vb + (size_t)bh * NTOK * DHEAD;

    float m = -1e30f;
#pragma unroll 1
    for (int c0 = 0; c0 < NTOK; c0 += 49) {
        const u16* kc = kbase + (size_t)c0 * DHEAD;
#pragma unroll 1
        for (int i = t; i < 49 * DHEAD; i += 256) sk[i] = bf2f(kc[i]);
        __syncthreads();
#pragma unroll 1
        for (int kk = 0; kk < 49; ++kk) {
            float e = dot96(qpk, &sk[kk * DHEAD]);
            m = fmaxf(m, e);
        }
        __syncthreads();
    }

    float l = 0.f;
    float acc[DHEAD];
#pragma unroll
    for (int d = 0; d < DHEAD; ++d) acc[d] = 0.f;

#pragma unroll 1
    for (int c0 = 0; c0 < NTOK; c0 += 49) {
        const u16* kc = kbase + (size_t)c0 * DHEAD;
        const u16* vc = vbase + (size_t)c0 * DHEAD;
#pragma unroll 1
        for (int i = t; i < 49 * DHEAD; i += 256) {
            sk[i] = bf2f(kc[i]);
            sv[i] = bf2f(vc[i]);
        }
        __syncthreads();
#pragma unroll 1
        for (int kk = 0; kk < 49; ++kk) {
            float e = dot96(qpk, &sk[kk * DHEAD]);
            float wgt = __expf(e - m);
            l += wgt;
            const float* vr = &sv[kk * DHEAD];
#pragma unroll
            for (int d = 0; d < DHEAD; ++d) acc[d] = fmaf(wgt, vr[d], acc[d]);
        }
        __syncthreads();
    }

    if (t < NTOK) {
        float scale = 1.0f / (l * 27.712812921102035f);  // softmax, THEN /sqrt(768)
        u16* orow = vbase + (size_t)t * DHEAD;           // in-place over own V slice
#pragma unroll
        for (int dp = 0; dp < 48; ++dp) {
            u32 lo = f2bf(acc[2 * dp] * scale);
            u32 hi = f2bf(acc[2 * dp + 1] * scale);
            ((u32*)orow)[dp] = lo | (hi << 16);
        }
    }
}

// ---------------------------------------------- K3: proj GEMM, MFMA + epilogue
// out(50176 x 768) = AO(50176 x 768, head-sliced bf16) @ Wproj + bias,
// then window-reverse + residual. Same tile structure as kvmm. Exact fit.
template<bool FP32>
__global__ __launch_bounds__(256, 2) void projmm_kernel(
    const u16* __restrict__ ao,            // (256*8,196,96) attn out (was V)
    const void* __restrict__ wpv, const void* __restrict__ bpv,
    const void* __restrict__ xv, const int* __restrict__ flag,
    void* __restrict__ outv)
{
    if (flag[0] != (FP32 ? 1 : 0)) return;
    __shared__ u16 As[128 * 40];
    __shared__ u16 Bs[128 * 40];

    int t = threadIdx.x;
    int mb = blockIdx.x % 392;
    int nb = blockIdx.x / 392;
    int n0 = nb * 128;

    // A staging: thread = (row, 16-col half); source ao row, head-sliced k
    int arow = t >> 1, ahalf = t & 1;
    int r = mb * 128 + arow;
    int wi = r / 196, tok = r - wi * 196;
    size_t aobase = (size_t)(wi * 8) * 196 + (size_t)tok;   // +h*196, *96+dd

    // B staging: thread = (k-pair kp, 8 cols cg*8..+7), natural cols
    int kp = t >> 4, cg = t & 15;

    f32x4 acc[4][4];
#pragma unroll
    for (int m = 0; m < 4; ++m)
#pragma unroll
        for (int n = 0; n < 4; ++n)
            acc[m][n] = (f32x4){0.f, 0.f, 0.f, 0.f};

    int lane = t & 63, wvid = t >> 6;
    int wm = wvid >> 1, wn = wvid & 1;
    int lo = lane & 15, hi = lane >> 4;

#pragma unroll 1
    for (int kk = 0; kk < 24; ++kk) {
        int k0 = kk * 32;
        // ---- stage A from ao (always bf16); 16-chunks never cross heads ----
        {
            int kabs = k0 + ahalf * 16;
            int h = kabs / 96, dd = kabs - h * 96;
            const uint4* ap = (const uint4*)(ao + (aobase + (size_t)h * 196) * 96 + dd);
            uint4 q0 = ap[0], q1 = ap[1];
            uint4* dst = (uint4*)&As[arow * 40 + ahalf * 16];
            dst[0] = q0; dst[1] = q1;
        }
        // ---- stage B from w_proj, transposed: Bt[c][k] ----
        if (FP32) {
            const float* w0p = (const float*)wpv + (size_t)(k0 + 2 * kp) * CDIM + n0 + cg * 8;
            const float* w1p = w0p + CDIM;
            float4 a0 = ((const float4*)w0p)[0], a1 = ((const float4*)w0p)[1];
            float4 c0 = ((const float4*)w1p)[0], c1 = ((const float4*)w1p)[1];
            *(u32*)&Bs[(cg * 8 + 0) * 40 + 2 * kp] = pack2bf(a0.x, c0.x);
            *(u32*)&Bs[(cg * 8 + 1) * 40 + 2 * kp] = pack2bf(a0.y, c0.y);
            *(u32*)&Bs[(cg * 8 + 2) * 40 + 2 * kp] = pack2bf(a0.z, c0.z);
            *(u32*)&Bs[(cg * 8 + 3) * 40 + 2 * kp] = pack2bf(a0.w, c0.w);
            *(u32*)&Bs[(cg * 8 + 4) * 40 + 2 * kp] = pack2bf(a1.x, c1.x);
            *(u32*)&Bs[(cg * 8 + 5) * 40 + 2 * kp] = pack2bf(a1.y, c1.y);
            *(u32*)&Bs[(cg * 8 + 6) * 40 + 2 * kp] = pack2bf(a1.z, c1.z);
            *(u32*)&Bs[(cg * 8 + 7) * 40 + 2 * kp] = pack2bf(a1.w, c1.w);
        } else {
            const u16* w0p = (const u16*)wpv + (size_t)(k0 + 2 * kp) * CDIM + n0 + cg * 8;
            const u16* w1p = w0p + CDIM;
            uint4 ua = *(const uint4*)w0p;   // 8 bf16, row k
            uint4 ub = *(const uint4*)w1p;   // 8 bf16, row k+1
            *(u32*)&Bs[(cg * 8 + 0) * 40 + 2 * kp] = (ua.x & 0xFFFFu) | (ub.x << 16);
            *(u32*)&Bs[(cg * 8 + 1) * 40 + 2 * kp] = (ua.x >> 16) | (ub.x & 0xFFFF0000u);
            *(u32*)&Bs[(cg * 8 + 2) * 40 + 2 * kp] = (ua.y & 0xFFFFu) | (ub.y << 16);
            *(u32*)&Bs[(cg * 8 + 3) * 40 + 2 * kp] = (ua.y >> 16) | (ub.y & 0xFFFF0000u);
            *(u32*)&Bs[(cg * 8 + 4) * 40 + 2 * kp] = (ua.z & 0xFFFFu) | (ub.z << 16);
            *(u32*)&Bs[(cg * 8 + 5) * 40 + 2 * kp] = (ua.z >> 16) | (ub.z & 0xFFFF0000u);
            *(u32*)&Bs[(cg * 8 + 6) * 40 + 2 * kp] = (ua.w & 0xFFFFu) | (ub.w << 16);
            *(u32*)&Bs[(cg * 8 + 7) * 40 + 2 * kp] = (ua.w >> 16) | (ub.w & 0xFFFF0000u);
        }
        __syncthreads();
        bf16x8 af[4], bfr[4];
#pragma unroll
        for (int m = 0; m < 4; ++m)
            af[m] = *(const bf16x8*)&As[(wm * 64 + m * 16 + lo) * 40 + hi * 8];
#pragma unroll
        for (int n = 0; n < 4; ++n)
            bfr[n] = *(const bf16x8*)&Bs[(wn * 64 + n * 16 + lo) * 40 + hi * 8];
#pragma unroll
        for (int m = 0; m < 4; ++m)
#pragma unroll
            for (int n = 0; n < 4; ++n)
                acc[m][n] = __builtin_amdgcn_mfma_f32_16x16x32_bf16(af[m], bfr[n], acc[m][n], 0, 0, 0);
        __syncthreads();
    }

    // ---- store: bias + window reverse + residual ----
    float bias[4];
    int col_[4];
#pragma unroll
    for (int n = 0; n < 4; ++n) {
        col_[n] = n0 + wn * 64 + n * 16 + lo;
        bias[n] = FP32 ? ((const float*)bpv)[col_[n]] : bf2f(((const u16*)bpv)[col_[n]]);
    }
#pragma unroll
    for (int m = 0; m < 4; ++m) {
#pragma unroll
        for (int j = 0; j < 4; ++j) {
            int rr = mb * 128 + wm * 64 + m * 16 + hi * 4 + j;
            int wi2 = rr / 196, tk = rr - wi2 * 196;
            int b2 = wi2 >> 4, wrem2 = wi2 & 15, wr2 = wrem2 >> 2, wc2 = wrem2 & 3;
            int tr2 = tk / 14, tc2 = tk - tr2 * 14;
            size_t obase = ((size_t)b2 * 3136 +
                            (size_t)((wr2 * 14 + tr2) * 56 + wc2 * 14 + tc2)) * CDIM;
#pragma unroll
            for (int n = 0; n < 4; ++n) {
                size_t off = obase + col_[n];
                if (FP32) {
                    ((float*)outv)[off] = acc[m][n][j] + bias[n] + ((const float*)xv)[off];
                } else {
                    ((u16*)outv)[off] =
                        f2bf(acc[m][n][j] + bias[n] + bf2f(((const u16*)xv)[off]));
                }
            }
        }
    }
}

extern "C" void kernel_launch(void* const* d_in, const int* in_sizes, int n_in,
                              void* d_out, int out_size, void* d_ws, size_t ws_size,
                              hipStream_t stream) {
    const void* x      = d_in[0];
    const void* w_qkv  = d_in[1];
    const void* b_qkv  = d_in[2];
    const void* w_proj = d_in[3];
    const void* b_proj = d_in[4];

    const size_t per = (size_t)NWIN * NHEAD * NTOK * DHEAD;  // 38,535,168 elems
    u16* kb = (u16*)d_ws;
    u16* vb = kb + per;                                      // after K2: attn out
    int* flag = (int*)((char*)d_ws + 2 * per * sizeof(u16)); // offset 154,140,672

    detect_kernel<<<1, 256, 0, stream>>>((const u16*)w_qkv, flag);

    // K1: 392 M-tiles x 12 d-tiles
    kvmm_kernel<false><<<4704, 256, 0, stream>>>(x, w_qkv, b_qkv, flag, kb, vb);
    kvmm_kernel<true ><<<4704, 256, 0, stream>>>(x, w_qkv, b_qkv, flag, kb, vb);

    qattn_kernel<false><<<NWIN * NHEAD, 256, 0, stream>>>(x, w_qkv, b_qkv, flag, kb, vb);
    qattn_kernel<true ><<<NWIN * NHEAD, 256, 0, stream>>>(x, w_qkv, b_qkv, flag, kb, vb);

    // K3: 392 M-tiles x 6 N-tiles
    projmm_kernel<false><<<2352, 256, 0, stream>>>(vb, w_proj, b_proj, x, flag, d_out);
    projmm_kernel<true ><<<2352, 256, 0, stream>>>(vb, w_proj, b_proj, x, flag, d_out);
}

// Round 2
// 1676.959 us; speedup vs baseline: 8.4344x; 4.5499x over previous
//
#include <hip/hip_runtime.h>

// WindowedMultiHeadAttention. B=16, 56x56 tokens, C=768, 8 heads x d=96,
// 14x14 windows -> 256 windows x 196 tokens.
// Round 4: qattn rewritten on MFMA bf16.
//   K1<FP32>: kb/vb = win_part(x) @ w_qkv[k,v cols] + bias   (MFMA, unchanged)
//   K2<FP32>: per-(window,head) block, 4 waves:
//     Phase A: Q(208x96 pad) = Xwin @ Wq_h + bias, MFMA BK=32, Q -> LDS.
//              Wave w owns query tiles {w, w+4, w+8, w+12} (<13) — same tiles
//              it consumes in phase B, so Q is wave-private.
//     Phase B: stage K[196][96->104 pad] and V^T[96][232 pad] in LDS; per
//              q-tile: S^T = mfma(K,Q) (col=q, row=key), per-lane softmax
//              (52 regs + shfl_xor 16/32), P prescaled by 1/(l*sqrt(768))
//              -> per-wave P LDS [16][232]; O = mfma(P, V^T) overwrites vb.
//   K3<FP32>: proj GEMM + bias + window reverse + residual    (MFMA, unchanged)
// LDS: Q 39,936 + union(phaseA 24,320 | K 43,264 + Vt 44,544 + P 29,696)
//      = 157,440 B static.
// ws: kb 77,070,336 B | vb/attn_out 77,070,336 B | flag 4 B  (154,140,676 B)

#define NWIN 256
#define NTOK 196
#define CDIM 768
#define NHEAD 8
#define DHEAD 96
#define C3 2304

typedef unsigned short u16;
typedef unsigned int u32;
typedef __attribute__((ext_vector_type(8))) short bf16x8;  // 8 bf16 (4 VGPRs)
typedef __attribute__((ext_vector_type(4))) float f32x4;   // MFMA C/D frag

__device__ __forceinline__ float bf2f(u16 u) {
    union { u32 i; float f; } cv;
    cv.i = ((u32)u) << 16;
    return cv.f;
}
__device__ __forceinline__ float2 bfp2f(u32 u) {
    union { u32 i; float f; } lo, hi;
    lo.i = u << 16;
    hi.i = u & 0xFFFF0000u;
    float2 r; r.x = lo.f; r.y = hi.f;
    return r;
}
__device__ __forceinline__ u16 f2bf(float f) {
    union { float f; u32 i; } cv;
    cv.f = f;
    u32 x = cv.i;
    x = x + 0x7FFFu + ((x >> 16) & 1u);   // RNE
    return (u16)(x >> 16);
}
__device__ __forceinline__ u32 pack2bf(float a, float b) {
    return (u32)f2bf(a) | ((u32)f2bf(b) << 16);
}

// ------------------------------------------------------------- dtype detect
// flag=1 -> inputs are fp32; flag=0 -> bf16.
__global__ void detect_kernel(const u16* __restrict__ w, int* __restrict__ flag) {
    __shared__ int any;
    int t = threadIdx.x;
    if (t == 0) any = 0;
    __syncthreads();
    int hit = 0;
    for (int i = 0; i < 16; ++i) {
        u16 u = w[t * 16 + i];
        int e = (u >> 7) & 0xFF;
        if (e >= 140) hit = 1;    // |val| >= 2^13: impossible for bf16 weights
    }
    if (hit) atomicOr(&any, 1);
    __syncthreads();
    if (t == 0) flag[0] = any;
}

// ---------------------------------------------------------- K1: KV GEMM, MFMA
template<bool FP32>
__global__ __launch_bounds__(256, 2) void kvmm_kernel(
    const void* __restrict__ xv, const void* __restrict__ wqv,
    const void* __restrict__ bvv, const int* __restrict__ flag,
    u16* __restrict__ kb, u16* __restrict__ vb)
{
    if (flag[0] != (FP32 ? 1 : 0)) return;
    __shared__ u16 As[128 * 40];   // A[row][k], 40-pad (80B stride)
    __shared__ u16 Bs[128 * 40];   // Bt[c][k] (col-major W tile)

    int t = threadIdx.x;
    int mb = blockIdx.x % 392;
    int nb = blockIdx.x / 392;

    int arow = t >> 1, ahalf = t & 1;
    int r = mb * 128 + arow;
    int wi = r / 196, tok = r - wi * 196;
    int b_ = wi >> 4, wrem = wi & 15, wr = wrem >> 2, wc = wrem & 3;
    int tr = tok / 14, tc = tok - tr * 14;
    size_t xrow = ((size_t)b_ * 3136 + (size_t)((wr * 14 + tr) * 56 + wc * 14 + tc)) * CDIM;

    int kp = t >> 4;      // k rows 2kp, 2kp+1
    int dg = t & 15;
    int scol[4];
#pragma unroll
    for (int i = 0; i < 4; ++i) {
        int d_abs = nb * 64 + dg * 4 + i;
        int h = d_abs / 96, dh = d_abs - h * 96;
        scol[i] = h * 288 + 3 * dh + 1;   // K col; V col = scol+1
    }

    f32x4 acc[4][4];
#pragma unroll
    for (int m = 0; m < 4; ++m)
#pragma unroll
        for (int n = 0; n < 4; ++n)
            acc[m][n] = (f32x4){0.f, 0.f, 0.f, 0.f};

    int lane = t & 63, wvid = t >> 6;
    int wm = wvid >> 1, wn = wvid & 1;
    int lo = lane & 15, hi = lane >> 4;

#pragma unroll 1
    for (int kk = 0; kk < 24; ++kk) {
        int k0 = kk * 32;
        {
            u32* dst = (u32*)&As[arow * 40 + ahalf * 16];
            if (FP32) {
                const float4* xp = (const float4*)((const float*)xv + xrow + k0 + ahalf * 16);
                float4 f0 = xp[0], f1 = xp[1], f2 = xp[2], f3 = xp[3];
                dst[0] = pack2bf(f0.x, f0.y); dst[1] = pack2bf(f0.z, f0.w);
                dst[2] = pack2bf(f1.x, f1.y); dst[3] = pack2bf(f1.z, f1.w);
                dst[4] = pack2bf(f2.x, f2.y); dst[5] = pack2bf(f2.z, f2.w);
                dst[6] = pack2bf(f3.x, f3.y); dst[7] = pack2bf(f3.z, f3.w);
            } else {
                const uint4* xp = (const uint4*)((const u16*)xv + xrow + k0 + ahalf * 16);
                uint4 q0 = xp[0], q1 = xp[1];
                ((uint4*)dst)[0] = q0;
                ((uint4*)dst)[1] = q1;
            }
        }
        if (FP32) {
            const float* w0p = (const float*)wqv + (size_t)(k0 + 2 * kp) * C3;
            const float* w1p = w0p + C3;
#pragma unroll
            for (int i = 0; i < 4; ++i) {
                int c = dg * 4 + i;
                float ka0 = w0p[scol[i]],     ka1 = w1p[scol[i]];
                float va0 = w0p[scol[i] + 1], va1 = w1p[scol[i] + 1];
                *(u32*)&Bs[(c)      * 40 + 2 * kp] = pack2bf(ka0, ka1);
                *(u32*)&Bs[(64 + c) * 40 + 2 * kp] = pack2bf(va0, va1);
            }
        } else {
            const u16* w0p = (const u16*)wqv + (size_t)(k0 + 2 * kp) * C3;
            const u16* w1p = w0p + C3;
#pragma unroll
            for (int i = 0; i < 4; ++i) {
                int c = dg * 4 + i;
                u32 ka0 = w0p[scol[i]],     ka1 = w1p[scol[i]];
                u32 va0 = w0p[scol[i] + 1], va1 = w1p[scol[i] + 1];
                *(u32*)&Bs[(c)      * 40 + 2 * kp] = ka0 | (ka1 << 16);
                *(u32*)&Bs[(64 + c) * 40 + 2 * kp] = va0 | (va1 << 16);
            }
        }
        __syncthreads();
        bf16x8 af[4], bfr[4];
#pragma unroll
        for (int m = 0; m < 4; ++m)
            af[m] = *(const bf16x8*)&As[(wm * 64 + m * 16 + lo) * 40 + hi * 8];
#pragma unroll
        for (int n = 0; n < 4; ++n)
            bfr[n] = *(const bf16x8*)&Bs[(wn * 64 + n * 16 + lo) * 40 + hi * 8];
#pragma unroll
        for (int m = 0; m < 4; ++m)
#pragma unroll
            for (int n = 0; n < 4; ++n)
                acc[m][n] = __builtin_amdgcn_mfma_f32_16x16x32_bf16(af[m], bfr[n], acc[m][n], 0, 0, 0);
        __syncthreads();
    }

    u16* obuf = wn ? vb : kb;
    float bias[4];
    int h_[4], dh_[4];
#pragma unroll
    for (int n = 0; n < 4; ++n) {
        int d_abs = nb * 64 + n * 16 + lo;
        h_[n] = d_abs / 96; dh_[n] = d_abs - h_[n] * 96;
        int bcol = h_[n] * 288 + 3 * dh_[n] + (wn ? 2 : 1);
        bias[n] = FP32 ? ((const float*)bvv)[bcol] : bf2f(((const u16*)bvv)[bcol]);
    }
#pragma unroll
    for (int m = 0; m < 4; ++m) {
#pragma unroll
        for (int j = 0; j < 4; ++j) {
            int rr = mb * 128 + wm * 64 + m * 16 + hi * 4 + j;
            int wi2 = rr / 196, tk = rr - wi2 * 196;
            size_t rowpart = (size_t)wi2 * (8 * 196) + (size_t)tk;
#pragma unroll
            for (int n = 0; n < 4; ++n) {
                size_t dst = (rowpart + (size_t)h_[n] * 196) * 96 + dh_[n];
                obuf[dst] = f2bf(acc[m][n][j] + bias[n]);
            }
        }
    }
}

// ------------------------------------------------- K2: MFMA Q-GEMM + attention
// block = (window, head), 4 waves. See header comment.
template<bool FP32>
__global__ __launch_bounds__(256) void qattn_kernel(
    const void* __restrict__ xv, const void* __restrict__ wv,
    const void* __restrict__ bvv, const int* __restrict__ flag,
    const u16* __restrict__ kb, u16* __restrict__ vb)
{
    if (flag[0] != (FP32 ? 1 : 0)) return;
    __shared__ u16 lds_q[208 * 96];       // 39,936 B  Q[qrow][d] (persistent)
    __shared__ u16 lds_r2[58752];         // 117,504 B (union region)
    u16* As  = lds_r2;                    // phase A: x tile   [208][40]
    u16* Bsw = lds_r2 + 208 * 40;         // phase A: Wq tile  [96][40] (col-major)
    u16* Kl  = lds_r2;                    // phase B: K tile   [208][104]
    u16* Vt  = lds_r2 + 208 * 104;        // phase B: V^T      [96][232]
    u16* Pl  = lds_r2 + 208 * 104 + 96 * 232;  // phase B: P per wave [4][16][232]

    int bh = blockIdx.x;                  // wi*8 + h
    int wi = bh >> 3;
    int h  = bh & 7;
    int t  = threadIdx.x;
    int lane = t & 63, w = t >> 6;
    int lo = lane & 15, hi = lane >> 4;

    int b = wi >> 4, wrem = wi & 15, wr = wrem >> 2, wc = wrem & 3;

    // staging rows for phase A (two rows per thread; rowB clamped)
    int rowA = t >> 1, half = t & 1;
    int rowB = 128 + (t >> 1);
    size_t xrowA, xrowB;
    {
        int rA = rowA / 14, cA = rowA - rA * 14;
        xrowA = ((size_t)b * 3136 + (size_t)((wr * 14 + rA) * 56 + wc * 14 + cA)) * CDIM;
        int tokB = rowB < NTOK ? rowB : (NTOK - 1);
        int rB = tokB / 14, cB = tokB - rB * 14;
        xrowB = ((size_t)b * 3136 + (size_t)((wr * 14 + rB) * 56 + wc * 14 + cB)) * CDIM;
    }

    // ---------------- Phase A: Q = Xwin @ Wq_h (MFMA) ----------------
    f32x4 qacc[4][6];
#pragma unroll
    for (int i = 0; i < 4; ++i)
#pragma unroll
        for (int n = 0; n < 6; ++n)
            qacc[i][n] = (f32x4){0.f, 0.f, 0.f, 0.f};

    int kp = t >> 4, dg = t & 15;         // Wq staging: k-pair, 6-col group

#pragma unroll 1
    for (int kk = 0; kk < 24; ++kk) {
        int k0 = kk * 32;
        // stage x rows -> As (bf16)
        {
            u32* dst = (u32*)&As[rowA * 40 + half * 16];
            if (FP32) {
                const float4* xp = (const float4*)((const float*)xv + xrowA + k0 + half * 16);
                float4 f0 = xp[0], f1 = xp[1], f2 = xp[2], f3 = xp[3];
                dst[0] = pack2bf(f0.x, f0.y); dst[1] = pack2bf(f0.z, f0.w);
                dst[2] = pack2bf(f1.x, f1.y); dst[3] = pack2bf(f1.z, f1.w);
                dst[4] = pack2bf(f2.x, f2.y); dst[5] = pack2bf(f2.z, f2.w);
                dst[6] = pack2bf(f3.x, f3.y); dst[7] = pack2bf(f3.z, f3.w);
            } else {
                const uint4* xp = (const uint4*)((const u16*)xv + xrowA + k0 + half * 16);
                ((uint4*)dst)[0] = xp[0];
                ((uint4*)dst)[1] = xp[1];
            }
            if (rowB < 208) {
                u32* dst2 = (u32*)&As[rowB * 40 + half * 16];
                if (FP32) {
                    const float4* xp = (const float4*)((const float*)xv + xrowB + k0 + half * 16);
                    float4 f0 = xp[0], f1 = xp[1], f2 = xp[2], f3 = xp[3];
                    dst2[0] = pack2bf(f0.x, f0.y); dst2[1] = pack2bf(f0.z, f0.w);
                    dst2[2] = pack2bf(f1.x, f1.y); dst2[3] = pack2bf(f1.z, f1.w);
                    dst2[4] = pack2bf(f2.x, f2.y); dst2[5] = pack2bf(f2.z, f2.w);
                    dst2[6] = pack2bf(f3.x, f3.y); dst2[7] = pack2bf(f3.z, f3.w);
                } else {
                    const uint4* xp = (const uint4*)((const u16*)xv + xrowB + k0 + half * 16);
                    ((uint4*)dst2)[0] = xp[0];
                    ((uint4*)dst2)[1] = xp[1];
                }
            }
        }
        // stage Wq tile (col-major): Bsw[c][k], source col = h*288 + 3c + 0
        if (FP32) {
            const float* w0p = (const float*)wv + (size_t)(k0 + 2 * kp) * C3 + h * 288;
            const float* w1p = w0p + C3;
#pragma unroll
            for (int i = 0; i < 6; ++i) {
                int c = dg * 6 + i;
                *(u32*)&Bsw[c * 40 + 2 * kp] = pack2bf(w0p[3 * c], w1p[3 * c]);
            }
        } else {
            const u16* w0p = (const u16*)wv + (size_t)(k0 + 2 * kp) * C3 + h * 288;
            const u16* w1p = w0p + C3;
#pragma unroll
            for (int i = 0; i < 6; ++i) {
                int c = dg * 6 + i;
                *(u32*)&Bsw[c * 40 + 2 * kp] = (u32)w0p[3 * c] | ((u32)w1p[3 * c] << 16);
            }
        }
        __syncthreads();
        bf16x8 bq[6];
#pragma unroll
        for (int n = 0; n < 6; ++n)
            bq[n] = *(const bf16x8*)&Bsw[(n * 16 + lo) * 40 + hi * 8];
#pragma unroll
        for (int i = 0; i < 4; ++i) {
            int qt = w + 4 * i;
            if (qt < 13) {
                bf16x8 af = *(const bf16x8*)&As[(qt * 16 + lo) * 40 + hi * 8];
#pragma unroll
                for (int n = 0; n < 6; ++n)
                    qacc[i][n] = __builtin_amdgcn_mfma_f32_16x16x32_bf16(af, bq[n], qacc[i][n], 0, 0, 0);
            }
        }
        __syncthreads();
    }

    // bias + write Q to LDS (wave-private rows)
    {
        float qb_[6];
#pragma unroll
        for (int n = 0; n < 6; ++n) {
            int d = n * 16 + lo;
            int bcol = h * 288 + 3 * d;
            qb_[n] = FP32 ? ((const float*)bvv)[bcol] : bf2f(((const u16*)bvv)[bcol]);
        }
#pragma unroll
        for (int i = 0; i < 4; ++i) {
            int qt = w + 4 * i;
            if (qt < 13) {
#pragma unroll
                for (int n = 0; n < 6; ++n)
#pragma unroll
                    for (int j = 0; j < 4; ++j)
                        lds_q[(qt * 16 + hi * 4 + j) * 96 + n * 16 + lo] =
                            f2bf(qacc[i][n][j] + qb_[n]);
            }
        }
    }

    // ---------------- Phase B staging: K, V^T (+zero pads) ----------------
    const u16* kbg = kb + (size_t)bh * NTOK * DHEAD;
    u16*       vbg = vb + (size_t)bh * NTOK * DHEAD;

    // K: 196 rows x 12 uint4 groups
#pragma unroll 1
    for (int i = t; i < 196 * 12; i += 256) {
        int row = i / 12, cg = i - row * 12;
        *(uint4*)&Kl[row * 104 + cg * 8] = *(const uint4*)(kbg + row * 96 + cg * 8);
    }
    // V^T: 98 token-pairs x 12 d-groups
#pragma unroll 1
    for (int i = t; i < 98 * 12; i += 256) {
        int tp = i / 12, dgv = i - tp * 12;
        const u16* v0 = vbg + (size_t)(2 * tp) * 96 + dgv * 8;
        uint4 a = *(const uint4*)v0;
        uint4 bb = *(const uint4*)(v0 + 96);
        int dbase = dgv * 8;
        int cpos = 2 * tp;
        *(u32*)&Vt[(dbase + 0) * 232 + cpos] = (a.x & 0xFFFFu) | (bb.x << 16);
        *(u32*)&Vt[(dbase + 1) * 232 + cpos] = (a.x >> 16) | (bb.x & 0xFFFF0000u);
        *(u32*)&Vt[(dbase + 2) * 232 + cpos] = (a.y & 0xFFFFu) | (bb.y << 16);
        *(u32*)&Vt[(dbase + 3) * 232 + cpos] = (a.y >> 16) | (bb.y & 0xFFFF0000u);
        *(u32*)&Vt[(dbase + 4) * 232 + cpos] = (a.z & 0xFFFFu) | (bb.z << 16);
        *(u32*)&Vt[(dbase + 5) * 232 + cpos] = (a.z >> 16) | (bb.z & 0xFFFF0000u);
        *(u32*)&Vt[(dbase + 6) * 232 + cpos] = (a.w & 0xFFFFu) | (bb.w << 16);
        *(u32*)&Vt[(dbase + 7) * 232 + cpos] = (a.w >> 16) | (bb.w & 0xFFFF0000u);
    }
    // zero V^T cols 196..223 (96 rows x 14 u32)
#pragma unroll 1
    for (int i = t; i < 96 * 14; i += 256) {
        int d = i / 14, c2 = i - d * 14;
        *(u32*)&Vt[d * 232 + 196 + 2 * c2] = 0;
    }
    __syncthreads();

    // ---------------- Phase B: per-wave attention over its q-tiles ----------
    u16* pw = Pl + w * (16 * 232);
#pragma unroll 1
    for (int i = 0; i < 4; ++i) {
        int qt = w + 4 * i;
        if (qt >= 13) break;
        // Q B-frags (3 k-steps of 32 over d=96)
        bf16x8 qf[3];
#pragma unroll
        for (int ks = 0; ks < 3; ++ks)
            qf[ks] = *(const bf16x8*)&lds_q[(qt * 16 + lo) * 96 + ks * 32 + hi * 8];
        // S^T: D[key][q] — A = K rows, B = Q
        f32x4 sc[13];
#pragma unroll
        for (int kt = 0; kt < 13; ++kt) sc[kt] = (f32x4){0.f, 0.f, 0.f, 0.f};
#pragma unroll 1
        for (int kt = 0; kt < 13; ++kt) {
#pragma unroll
            for (int ks = 0; ks < 3; ++ks) {
                bf16x8 kf = *(const bf16x8*)&Kl[(kt * 16 + lo) * 104 + ks * 32 + hi * 8];
                sc[kt] = __builtin_amdgcn_mfma_f32_16x16x32_bf16(kf, qf[ks], sc[kt], 0, 0, 0);
            }
        }
        // softmax for query q = qt*16 + lo (this lane's column)
        float p[52];
        float mx = -1e30f;
#pragma unroll
        for (int kt = 0; kt < 13; ++kt)
#pragma unroll
            for (int j = 0; j < 4; ++j) {
                float e = sc[kt][j];
                if (kt == 12 && hi != 0) e = -1e30f;   // keys >= 196
                p[kt * 4 + j] = e;
                mx = fmaxf(mx, e);
            }
        mx = fmaxf(mx, __shfl_xor(mx, 16));
        mx = fmaxf(mx, __shfl_xor(mx, 32));
        float l = 0.f;
#pragma unroll
        for (int z = 0; z < 52; ++z) {
            float e = __expf(p[z] - mx);
            p[z] = e;
            l += e;
        }
        l += __shfl_xor(l, 16);
        l += __shfl_xor(l, 32);
        float rs = 1.0f / (l * 27.712812921102035f);   // softmax, THEN /sqrt(768)
        // write P (pre-scaled) to per-wave LDS: P[q=lo][key]
#pragma unroll
        for (int kt = 0; kt < 13; ++kt) {
            *(u32*)&pw[lo * 232 + kt * 16 + hi * 4]     = pack2bf(p[kt * 4 + 0] * rs, p[kt * 4 + 1] * rs);
            *(u32*)&pw[lo * 232 + kt * 16 + hi * 4 + 2] = pack2bf(p[kt * 4 + 2] * rs, p[kt * 4 + 3] * rs);
        }
        *(u32*)&pw[lo * 232 + 208 + hi * 4]     = 0;   // zero keys 208..223
        *(u32*)&pw[lo * 232 + 208 + hi * 4 + 2] = 0;
        asm volatile("s_waitcnt lgkmcnt(0)" ::: "memory");
        __builtin_amdgcn_sched_barrier(0);
        // PV: O[q][d] — A = P, B = V^T
        f32x4 oa[6];
#pragma unroll
        for (int n = 0; n < 6; ++n) oa[n] = (f32x4){0.f, 0.f, 0.f, 0.f};
#pragma unroll 1
        for (int ks = 0; ks < 7; ++ks) {
            bf16x8 pf = *(const bf16x8*)&pw[lo * 232 + ks * 32 + hi * 8];
#pragma unroll
            for (int n = 0; n < 6; ++n) {
                bf16x8 vf = *(const bf16x8*)&Vt[(n * 16 + lo) * 232 + ks * 32 + hi * 8];
                oa[n] = __builtin_amdgcn_mfma_f32_16x16x32_bf16(pf, vf, oa[n], 0, 0, 0);
            }
        }
        // write O over this block's V slice
#pragma unroll
        for (int n = 0; n < 6; ++n)
#pragma unroll
            for (int j = 0; j < 4; ++j) {
                int q = qt * 16 + hi * 4 + j;
                if (q < NTOK)
                    vbg[(size_t)q * 96 + n * 16 + lo] = f2bf(oa[n][j]);
            }
    }
}

// ---------------------------------------------- K3: proj GEMM, MFMA + epilogue
template<bool FP32>
__global__ __launch_bounds__(256, 2) void projmm_kernel(
    const u16* __restrict__ ao,            // (256*8,196,96) attn out (was V)
    const void* __restrict__ wpv, const void* __restrict__ bpv,
    const void* __restrict__ xv, const int* __restrict__ flag,
    void* __restrict__ outv)
{
    if (flag[0] != (FP32 ? 1 : 0)) return;
    __shared__ u16 As[128 * 40];
    __shared__ u16 Bs[128 * 40];

    int t = threadIdx.x;
    int mb = blockIdx.x % 392;
    int nb = blockIdx.x / 392;
    int n0 = nb * 128;

    int arow = t >> 1, ahalf = t & 1;
    int r = mb * 128 + arow;
    int wi = r / 196, tok = r - wi * 196;
    size_t aobase = (size_t)(wi * 8) * 196 + (size_t)tok;

    int kp = t >> 4, cg = t & 15;

    f32x4 acc[4][4];
#pragma unroll
    for (int m = 0; m < 4; ++m)
#pragma unroll
        for (int n = 0; n < 4; ++n)
            acc[m][n] = (f32x4){0.f, 0.f, 0.f, 0.f};

    int lane = t & 63, wvid = t >> 6;
    int wm = wvid >> 1, wn = wvid & 1;
    int lo = lane & 15, hi = lane >> 4;

#pragma unroll 1
    for (int kk = 0; kk < 24; ++kk) {
        int k0 = kk * 32;
        {
            int kabs = k0 + ahalf * 16;
            int h = kabs / 96, dd = kabs - h * 96;
            const uint4* ap = (const uint4*)(ao + (aobase + (size_t)h * 196) * 96 + dd);
            uint4 q0 = ap[0], q1 = ap[1];
            uint4* dst = (uint4*)&As[arow * 40 + ahalf * 16];
            dst[0] = q0; dst[1] = q1;
        }
        if (FP32) {
            const float* w0p = (const float*)wpv + (size_t)(k0 + 2 * kp) * CDIM + n0 + cg * 8;
            const float* w1p = w0p + CDIM;
            float4 a0 = ((const float4*)w0p)[0], a1 = ((const float4*)w0p)[1];
            float4 c0 = ((const float4*)w1p)[0], c1 = ((const float4*)w1p)[1];
            *(u32*)&Bs[(cg * 8 + 0) * 40 + 2 * kp] = pack2bf(a0.x, c0.x);
            *(u32*)&Bs[(cg * 8 + 1) * 40 + 2 * kp] = pack2bf(a0.y, c0.y);
            *(u32*)&Bs[(cg * 8 + 2) * 40 + 2 * kp] = pack2bf(a0.z, c0.z);
            *(u32*)&Bs[(cg * 8 + 3) * 40 + 2 * kp] = pack2bf(a0.w, c0.w);
            *(u32*)&Bs[(cg * 8 + 4) * 40 + 2 * kp] = pack2bf(a1.x, c1.x);
            *(u32*)&Bs[(cg * 8 + 5) * 40 + 2 * kp] = pack2bf(a1.y, c1.y);
            *(u32*)&Bs[(cg * 8 + 6) * 40 + 2 * kp] = pack2bf(a1.z, c1.z);
            *(u32*)&Bs[(cg * 8 + 7) * 40 + 2 * kp] = pack2bf(a1.w, c1.w);
        } else {
            const u16* w0p = (const u16*)wpv + (size_t)(k0 + 2 * kp) * CDIM + n0 + cg * 8;
            const u16* w1p = w0p + CDIM;
            uint4 ua = *(const uint4*)w0p;
            uint4 ub = *(const uint4*)w1p;
            *(u32*)&Bs[(cg * 8 + 0) * 40 + 2 * kp] = (ua.x & 0xFFFFu) | (ub.x << 16);
            *(u32*)&Bs[(cg * 8 + 1) * 40 + 2 * kp] = (ua.x >> 16) | (ub.x & 0xFFFF0000u);
            *(u32*)&Bs[(cg * 8 + 2) * 40 + 2 * kp] = (ua.y & 0xFFFFu) | (ub.y << 16);
            *(u32*)&Bs[(cg * 8 + 3) * 40 + 2 * kp] = (ua.y >> 16) | (ub.y & 0xFFFF0000u);
            *(u32*)&Bs[(cg * 8 + 4) * 40 + 2 * kp] = (ua.z & 0xFFFFu) | (ub.z << 16);
            *(u32*)&Bs[(cg * 8 + 5) * 40 + 2 * kp] = (ua.z >> 16) | (ub.z & 0xFFFF0000u);
            *(u32*)&Bs[(cg * 8 + 6) * 40 + 2 * kp] = (ua.w & 0xFFFFu) | (ub.w << 16);
            *(u32*)&Bs[(cg * 8 + 7) * 40 + 2 * kp] = (ua.w >> 16) | (ub.w & 0xFFFF0000u);
        }
        __syncthreads();
        bf16x8 af[4], bfr[4];
#pragma unroll
        for (int m = 0; m < 4; ++m)
            af[m] = *(const bf16x8*)&As[(wm * 64 + m * 16 + lo) * 40 + hi * 8];
#pragma unroll
        for (int n = 0; n < 4; ++n)
            bfr[n] = *(const bf16x8*)&Bs[(wn * 64 + n * 16 + lo) * 40 + hi * 8];
#pragma unroll
        for (int m = 0; m < 4; ++m)
#pragma unroll
            for (int n = 0; n < 4; ++n)
                acc[m][n] = __builtin_amdgcn_mfma_f32_16x16x32_bf16(af[m], bfr[n], acc[m][n], 0, 0, 0);
        __syncthreads();
    }

    float bias[4];
    int col_[4];
#pragma unroll
    for (int n = 0; n < 4; ++n) {
        col_[n] = n0 + wn * 64 + n * 16 + lo;
        bias[n] = FP32 ? ((const float*)bpv)[col_[n]] : bf2f(((const u16*)bpv)[col_[n]]);
    }
#pragma unroll
    for (int m = 0; m < 4; ++m) {
#pragma unroll
        for (int j = 0; j < 4; ++j) {
            int rr = mb * 128 + wm * 64 + m * 16 + hi * 4 + j;
            int wi2 = rr / 196, tk = rr - wi2 * 196;
            int b2 = wi2 >> 4, wrem2 = wi2 & 15, wr2 = wrem2 >> 2, wc2 = wrem2 & 3;
            int tr2 = tk / 14, tc2 = tk - tr2 * 14;
            size_t obase = ((size_t)b2 * 3136 +
                            (size_t)((wr2 * 14 + tr2) * 56 + wc2 * 14 + tc2)) * CDIM;
#pragma unroll
            for (int n = 0; n < 4; ++n) {
                size_t off = obase + col_[n];
                if (FP32) {
                    ((float*)outv)[off] = acc[m][n][j] + bias[n] + ((const float*)xv)[off];
                } else {
                    ((u16*)outv)[off] =
                        f2bf(acc[m][n][j] + bias[n] + bf2f(((const u16*)xv)[off]));
                }
            }
        }
    }
}

extern "C" void kernel_launch(void* const* d_in, const int* in_sizes, int n_in,
                              void* d_out, int out_size, void* d_ws, size_t ws_size,
                              hipStream_t stream) {
    const void* x      = d_in[0];
    const void* w_qkv  = d_in[1];
    const void* b_qkv  = d_in[2];
    const void* w_proj = d_in[3];
    const void* b_proj = d_in[4];

    const size_t per = (size_t)NWIN * NHEAD * NTOK * DHEAD;  // 38,535,168 elems
    u16* kb = (u16*)d_ws;
    u16* vb = kb + per;                                      // after K2: attn out
    int* flag = (int*)((char*)d_ws + 2 * per * sizeof(u16)); // offset 154,140,672

    detect_kernel<<<1, 256, 0, stream>>>((const u16*)w_qkv, flag);

    kvmm_kernel<false><<<4704, 256, 0, stream>>>(x, w_qkv, b_qkv, flag, kb, vb);
    kvmm_kernel<true ><<<4704, 256, 0, stream>>>(x, w_qkv, b_qkv, flag, kb, vb);

    qattn_kernel<false><<<NWIN * NHEAD, 256, 0, stream>>>(x, w_qkv, b_qkv, flag, kb, vb);
    qattn_kernel<true ><<<NWIN * NHEAD, 256, 0, stream>>>(x, w_qkv, b_qkv, flag, kb, vb);

    projmm_kernel<false><<<2352, 256, 0, stream>>>(vb, w_proj, b_proj, x, flag, d_out);
    projmm_kernel<true ><<<2352, 256, 0, stream>>>(vb, w_proj, b_proj, x, flag, d_out);
}

// Round 3
// 952.425 us; speedup vs baseline: 14.8507x; 1.7607x over previous
//
#include <hip/hip_runtime.h>

// WindowedMultiHeadAttention. B=16, 56x56 tokens, C=768, 8 heads x d=96,
// 14x14 windows -> 256 windows x 196 tokens.
// Round 5: merged QKV GEMM (K1 computes q,k,v; Q no longer computed in K2);
// K2 is a slim attention kernel: Q/K frags direct from global (16B uint4),
// only V^T + P in LDS (74,240 B -> 2 blocks/CU), sc[] fully unrolled into
// registers, V^T staging bank-conflict-free. Host adapts to ws_size:
//   big ws:  [qb 77MB][kb 77MB][vb/attn-out 77MB][flag]   one pass
//   small ws:[ao 77MB][qb_c][kb_c][vb_c 3x19.3MB][flag]   4 window-chunks
// ws: qb 77,070,336 | kb 77,070,336 | vb/attn_out 77,070,336 | flag 4
//     (231,211,012 B; falls back to 134,873,092 B layout if less provided)

#define NWIN 256
#define NTOK 196
#define CDIM 768
#define NHEAD 8
#define DHEAD 96
#define C3 2304

typedef unsigned short u16;
typedef unsigned int u32;
typedef __attribute__((ext_vector_type(8))) short bf16x8;  // 8 bf16 (4 VGPRs)
typedef __attribute__((ext_vector_type(4))) float f32x4;   // MFMA C/D frag

__device__ __forceinline__ float bf2f(u16 u) {
    union { u32 i; float f; } cv;
    cv.i = ((u32)u) << 16;
    return cv.f;
}
__device__ __forceinline__ float2 bfp2f(u32 u) {
    union { u32 i; float f; } lo, hi;
    lo.i = u << 16;
    hi.i = u & 0xFFFF0000u;
    float2 r; r.x = lo.f; r.y = hi.f;
    return r;
}
__device__ __forceinline__ u16 f2bf(float f) {
    union { float f; u32 i; } cv;
    cv.f = f;
    u32 x = cv.i;
    x = x + 0x7FFFu + ((x >> 16) & 1u);   // RNE
    return (u16)(x >> 16);
}
__device__ __forceinline__ u32 pack2bf(float a, float b) {
    return (u32)f2bf(a) | ((u32)f2bf(b) << 16);
}

// ------------------------------------------------------------- dtype detect
// flag=1 -> inputs are fp32; flag=0 -> bf16.
__global__ void detect_kernel(const u16* __restrict__ w, int* __restrict__ flag) {
    __shared__ int any;
    int t = threadIdx.x;
    if (t == 0) any = 0;
    __syncthreads();
    int hit = 0;
    for (int i = 0; i < 16; ++i) {
        u16 u = w[t * 16 + i];
        int e = (u >> 7) & 0xFF;
        if (e >= 140) hit = 1;    // |val| >= 2^13: impossible for bf16 weights
    }
    if (hit) atomicOr(&any, 1);
    __syncthreads();
    if (t == 0) flag[0] = any;
}

// --------------------------------------------------------- K1: QKV GEMM, MFMA
// C(rows x 2304) = Xwin(rows x 768) @ Wqkv, rows chunk-relative.
// Block tile 128 x 192, where 192 cols = {q,k,v} x 64 d-values (nb*64..+63).
// Tile col c: which = c/64 (0=q,1=k,2=v), d_local = c%64.
// Source col for (d_abs, which) = h*288 + 3*(d_abs%96) + which -> each staging
// thread's 12 cols are CONTIGUOUS in w_qkv. 4 waves (2x2), wave = 64 x 96.
template<bool FP32>
__global__ __launch_bounds__(256, 2) void qkvmm_kernel(
    const void* __restrict__ xv, const void* __restrict__ wqv,
    const void* __restrict__ bvv, const int* __restrict__ flag,
    u16* __restrict__ qb, u16* __restrict__ kb, u16* __restrict__ vb,
    int win0, int mtiles)
{
    if (flag[0] != (FP32 ? 1 : 0)) return;
    __shared__ u16 As[128 * 40];   // A[row][k], 40-pad (80B stride)
    __shared__ u16 Bs[192 * 40];   // Bt[c][k] (col-major W tile)

    int t = threadIdx.x;
    int mb = blockIdx.x % mtiles;
    int nb = blockIdx.x / mtiles;          // 0..11 (64 d-values each)

    // ---- A staging coords: thread = (row, 16-col half) ----
    int arow = t >> 1, ahalf = t & 1;
    int rloc = mb * 128 + arow;            // chunk-relative row
    int wiL = rloc / 196, tok = rloc - wiL * 196;
    int wiA = win0 + wiL;                  // absolute window
    int b_ = wiA >> 4, wrem = wiA & 15, wr = wrem >> 2, wc = wrem & 3;
    int tr = tok / 14, tc = tok - tr * 14;
    size_t xrow = ((size_t)b_ * 3136 + (size_t)((wr * 14 + tr) * 56 + wc * 14 + tc)) * CDIM;

    // ---- B staging coords: thread = (k-pair kp, 12 contiguous src cols) ----
    int kp = t >> 4, dg = t & 15;
    int d0 = nb * 64 + dg * 4;             // 4 d-values, never cross a head
    int hB = d0 / 96, dh0 = d0 - hB * 96;
    int sb = hB * 288 + 3 * dh0;           // 12 contiguous source cols

    f32x4 acc[4][6];
#pragma unroll
    for (int m = 0; m < 4; ++m)
#pragma unroll
        for (int n = 0; n < 6; ++n)
            acc[m][n] = (f32x4){0.f, 0.f, 0.f, 0.f};

    int lane = t & 63, wvid = t >> 6;
    int wm = wvid >> 1, wn = wvid & 1;
    int lo = lane & 15, hi = lane >> 4;

#pragma unroll 1
    for (int kk = 0; kk < 24; ++kk) {
        int k0 = kk * 32;
        // ---- stage A (x -> bf16) ----
        {
            u32* dst = (u32*)&As[arow * 40 + ahalf * 16];
            if (FP32) {
                const float4* xp = (const float4*)((const float*)xv + xrow + k0 + ahalf * 16);
                float4 f0 = xp[0], f1 = xp[1], f2 = xp[2], f3 = xp[3];
                dst[0] = pack2bf(f0.x, f0.y); dst[1] = pack2bf(f0.z, f0.w);
                dst[2] = pack2bf(f1.x, f1.y); dst[3] = pack2bf(f1.z, f1.w);
                dst[4] = pack2bf(f2.x, f2.y); dst[5] = pack2bf(f2.z, f2.w);
                dst[6] = pack2bf(f3.x, f3.y); dst[7] = pack2bf(f3.z, f3.w);
            } else {
                const uint4* xp = (const uint4*)((const u16*)xv + xrow + k0 + ahalf * 16);
                ((uint4*)dst)[0] = xp[0];
                ((uint4*)dst)[1] = xp[1];
            }
        }
        // ---- stage B: 12 contiguous src cols x 2 k-rows, scatter to Bs ----
        if (FP32) {
            const float* w0p = (const float*)wqv + (size_t)(k0 + 2 * kp) * C3 + sb;
            const float* w1p = w0p + C3;
#pragma unroll
            for (int e = 0; e < 12; ++e) {
                int c = (e % 3) * 64 + dg * 4 + e / 3;
                *(u32*)&Bs[c * 40 + 2 * kp] = pack2bf(w0p[e], w1p[e]);
            }
        } else {
            const u16* w0p = (const u16*)wqv + (size_t)(k0 + 2 * kp) * C3 + sb;
            const u16* w1p = w0p + C3;
#pragma unroll
            for (int e = 0; e < 12; ++e) {
                int c = (e % 3) * 64 + dg * 4 + e / 3;
                *(u32*)&Bs[c * 40 + 2 * kp] = (u32)w0p[e] | ((u32)w1p[e] << 16);
            }
        }
        __syncthreads();
        // ---- fragments + MFMA ----
        bf16x8 af[4], bfr[6];
#pragma unroll
        for (int m = 0; m < 4; ++m)
            af[m] = *(const bf16x8*)&As[(wm * 64 + m * 16 + lo) * 40 + hi * 8];
#pragma unroll
        for (int n = 0; n < 6; ++n)
            bfr[n] = *(const bf16x8*)&Bs[(wn * 96 + n * 16 + lo) * 40 + hi * 8];
#pragma unroll
        for (int m = 0; m < 4; ++m)
#pragma unroll
            for (int n = 0; n < 6; ++n)
                acc[m][n] = __builtin_amdgcn_mfma_f32_16x16x32_bf16(af[m], bfr[n], acc[m][n], 0, 0, 0);
        __syncthreads();
    }

    // ---- store (+bias). D frag: col = lo, row = hi*4 + j ----
    float bias[6];
    int h2_[6], dh2_[6], wh_[6];
#pragma unroll
    for (int n = 0; n < 6; ++n) {
        int c = wn * 96 + n * 16 + lo;
        wh_[n] = c >> 6;                       // 0=q, 1=k, 2=v
        int d_abs = nb * 64 + (c & 63);
        h2_[n] = d_abs / 96; dh2_[n] = d_abs - h2_[n] * 96;
        int bcol = h2_[n] * 288 + 3 * dh2_[n] + wh_[n];
        bias[n] = FP32 ? ((const float*)bvv)[bcol] : bf2f(((const u16*)bvv)[bcol]);
    }
#pragma unroll
    for (int m = 0; m < 4; ++m) {
#pragma unroll
        for (int j = 0; j < 4; ++j) {
            int rr = mb * 128 + wm * 64 + m * 16 + hi * 4 + j;   // chunk-relative
            int wir = rr / 196, tk = rr - wir * 196;
            size_t rowpart = (size_t)wir * (8 * 196) + (size_t)tk;
#pragma unroll
            for (int n = 0; n < 6; ++n) {
                u16* ob = wh_[n] == 0 ? qb : (wh_[n] == 1 ? kb : vb);
                ob[(rowpart + (size_t)h2_[n] * 196) * 96 + dh2_[n]] =
                    f2bf(acc[m][n][j] + bias[n]);
            }
        }
    }
}

// ------------------------------------------------------ K2: attention (slim)
// block = (wi_rel, head), 4 waves; wave owns q-tiles {w, w+4, w+8, w+12} < 13.
// Q/K frags read directly from global (uint4, 16B-aligned). LDS: V^T + P only
// -> 74,240 B -> 2 blocks/CU. sc[] fully unrolled (registers).
template<bool FP32>
__global__ __launch_bounds__(256, 2) void attn_kernel(
    const u16* __restrict__ qbp, const u16* __restrict__ kbp,
    const u16* __restrict__ vbp, u16* __restrict__ ao,
    const int* __restrict__ flag, int win0)
{
    if (flag[0] != (FP32 ? 1 : 0)) return;
    __shared__ u16 Vt[96 * 232];          // 44,544 B  V^T[d][key], keys 196-223 zero
    __shared__ u16 Pl[4 * 16 * 232];      // 29,696 B  per-wave P[q][key]

    int bh = blockIdx.x;                  // wi_rel*8 + h
    int t  = threadIdx.x;
    int lane = t & 63, w = t >> 6;
    int lo = lane & 15, hi = lane >> 4;

    const u16* qbase = qbp + (size_t)bh * (NTOK * DHEAD);
    const u16* kbase = kbp + (size_t)bh * (NTOK * DHEAD);
    const u16* vbase = vbp + (size_t)bh * (NTOK * DHEAD);
    u16* obase = ao + ((size_t)bh + (size_t)win0 * 8) * (NTOK * DHEAD);

    // ---- stage V^T (tp varies fastest -> consecutive banks); zero pads ----
#pragma unroll 1
    for (int i = t; i < 112 * 12; i += 256) {
        int tp = i % 112, dgv = i / 112;
        int dbase = dgv * 8, cpos = 2 * tp;
        uint4 a = {0, 0, 0, 0}, bq = {0, 0, 0, 0};
        if (tp < 98) {
            const u16* v0 = vbase + (size_t)(2 * tp) * 96 + dbase;
            a  = *(const uint4*)v0;
            bq = *(const uint4*)(v0 + 96);
        }
        *(u32*)&Vt[(dbase + 0) * 232 + cpos] = (a.x & 0xFFFFu) | (bq.x << 16);
        *(u32*)&Vt[(dbase + 1) * 232 + cpos] = (a.x >> 16) | (bq.x & 0xFFFF0000u);
        *(u32*)&Vt[(dbase + 2) * 232 + cpos] = (a.y & 0xFFFFu) | (bq.y << 16);
        *(u32*)&Vt[(dbase + 3) * 232 + cpos] = (a.y >> 16) | (bq.y & 0xFFFF0000u);
        *(u32*)&Vt[(dbase + 4) * 232 + cpos] = (a.z & 0xFFFFu) | (bq.z << 16);
        *(u32*)&Vt[(dbase + 5) * 232 + cpos] = (a.z >> 16) | (bq.z & 0xFFFF0000u);
        *(u32*)&Vt[(dbase + 6) * 232 + cpos] = (a.w & 0xFFFFu) | (bq.w << 16);
        *(u32*)&Vt[(dbase + 7) * 232 + cpos] = (a.w >> 16) | (bq.w & 0xFFFF0000u);
    }
    __syncthreads();

    u16* pw = Pl + w * (16 * 232);
#pragma unroll 1
    for (int i = 0; i < 4; ++i) {
        int qt = w + 4 * i;
        if (qt >= 13) break;
        // Q B-frags direct from global (rows >=196 clamped; outputs masked)
        int qrow = qt * 16 + lo; if (qrow > 195) qrow = 195;
        bf16x8 qf[3];
#pragma unroll
        for (int ks = 0; ks < 3; ++ks)
            qf[ks] = *(const bf16x8*)(qbase + (size_t)qrow * 96 + ks * 32 + hi * 8);
        // S^T = K @ Q^T : D[key][q]; K A-frags direct from global
        f32x4 sc[13];
#pragma unroll
        for (int kt = 0; kt < 13; ++kt) sc[kt] = (f32x4){0.f, 0.f, 0.f, 0.f};
#pragma unroll
        for (int kt = 0; kt < 13; ++kt) {
            int krow = kt * 16 + lo; if (krow > 195) krow = 195;
            const u16* kr = kbase + (size_t)krow * 96;
#pragma unroll
            for (int ks = 0; ks < 3; ++ks) {
                bf16x8 kf = *(const bf16x8*)(kr + ks * 32 + hi * 8);
                sc[kt] = __builtin_amdgcn_mfma_f32_16x16x32_bf16(kf, qf[ks], sc[kt], 0, 0, 0);
            }
        }
        // softmax for query q = qt*16 + lo (this lane's column)
        float p[52];
        float mx = -1e30f;
#pragma unroll
        for (int kt = 0; kt < 13; ++kt)
#pragma unroll
            for (int j = 0; j < 4; ++j) {
                float e = sc[kt][j];
                if (kt == 12 && hi != 0) e = -1e30f;   // keys >= 196
                p[kt * 4 + j] = e;
                mx = fmaxf(mx, e);
            }
        mx = fmaxf(mx, __shfl_xor(mx, 16));
        mx = fmaxf(mx, __shfl_xor(mx, 32));
        float l = 0.f;
#pragma unroll
        for (int z = 0; z < 52; ++z) {
            float e = __expf(p[z] - mx);
            p[z] = e;
            l += e;
        }
        l += __shfl_xor(l, 16);
        l += __shfl_xor(l, 32);
        float rs = 1.0f / (l * 27.712812921102035f);   // softmax, THEN /sqrt(768)
        // write P (pre-scaled) to per-wave LDS: P[q=lo][key]
#pragma unroll
        for (int kt = 0; kt < 13; ++kt) {
            *(u32*)&pw[lo * 232 + kt * 16 + hi * 4]     = pack2bf(p[kt * 4 + 0] * rs, p[kt * 4 + 1] * rs);
            *(u32*)&pw[lo * 232 + kt * 16 + hi * 4 + 2] = pack2bf(p[kt * 4 + 2] * rs, p[kt * 4 + 3] * rs);
        }
        *(u32*)&pw[lo * 232 + 208 + hi * 4]     = 0;   // zero keys 208..223
        *(u32*)&pw[lo * 232 + 208 + hi * 4 + 2] = 0;
        asm volatile("s_waitcnt lgkmcnt(0)" ::: "memory");
        __builtin_amdgcn_sched_barrier(0);
        // PV: O[q][d] — A = P, B = V^T
        f32x4 oa[6];
#pragma unroll
        for (int n = 0; n < 6; ++n) oa[n] = (f32x4){0.f, 0.f, 0.f, 0.f};
#pragma unroll
        for (int ks = 0; ks < 7; ++ks) {
            bf16x8 pf = *(const bf16x8*)&pw[lo * 232 + ks * 32 + hi * 8];
#pragma unroll
            for (int n = 0; n < 6; ++n) {
                bf16x8 vf = *(const bf16x8*)&Vt[(n * 16 + lo) * 232 + ks * 32 + hi * 8];
                oa[n] = __builtin_amdgcn_mfma_f32_16x16x32_bf16(pf, vf, oa[n], 0, 0, 0);
            }
        }
        // store O (absolute-indexed attn-out)
#pragma unroll
        for (int n = 0; n < 6; ++n)
#pragma unroll
            for (int j = 0; j < 4; ++j) {
                int q = qt * 16 + hi * 4 + j;
                if (q < NTOK)
                    obase[(size_t)q * 96 + n * 16 + lo] = f2bf(oa[n][j]);
            }
    }
}

// ---------------------------------------------- K3: proj GEMM, MFMA + epilogue
template<bool FP32>
__global__ __launch_bounds__(256, 2) void projmm_kernel(
    const u16* __restrict__ ao,            // (256*8,196,96) attn out
    const void* __restrict__ wpv, const void* __restrict__ bpv,
    const void* __restrict__ xv, const int* __restrict__ flag,
    void* __restrict__ outv)
{
    if (flag[0] != (FP32 ? 1 : 0)) return;
    __shared__ u16 As[128 * 40];
    __shared__ u16 Bs[128 * 40];

    int t = threadIdx.x;
    int mb = blockIdx.x % 392;
    int nb = blockIdx.x / 392;
    int n0 = nb * 128;

    int arow = t >> 1, ahalf = t & 1;
    int r = mb * 128 + arow;
    int wi = r / 196, tok = r - wi * 196;
    size_t aobase = (size_t)(wi * 8) * 196 + (size_t)tok;

    int kp = t >> 4, cg = t & 15;

    f32x4 acc[4][4];
#pragma unroll
    for (int m = 0; m < 4; ++m)
#pragma unroll
        for (int n = 0; n < 4; ++n)
            acc[m][n] = (f32x4){0.f, 0.f, 0.f, 0.f};

    int lane = t & 63, wvid = t >> 6;
    int wm = wvid >> 1, wn = wvid & 1;
    int lo = lane & 15, hi = lane >> 4;

#pragma unroll 1
    for (int kk = 0; kk < 24; ++kk) {
        int k0 = kk * 32;
        {
            int kabs = k0 + ahalf * 16;
            int h = kabs / 96, dd = kabs - h * 96;
            const uint4* ap = (const uint4*)(ao + (aobase + (size_t)h * 196) * 96 + dd);
            uint4 q0 = ap[0], q1 = ap[1];
            uint4* dst = (uint4*)&As[arow * 40 + ahalf * 16];
            dst[0] = q0; dst[1] = q1;
        }
        if (FP32) {
            const float* w0p = (const float*)wpv + (size_t)(k0 + 2 * kp) * CDIM + n0 + cg * 8;
            const float* w1p = w0p + CDIM;
            float4 a0 = ((const float4*)w0p)[0], a1 = ((const float4*)w0p)[1];
            float4 c0 = ((const float4*)w1p)[0], c1 = ((const float4*)w1p)[1];
            *(u32*)&Bs[(cg * 8 + 0) * 40 + 2 * kp] = pack2bf(a0.x, c0.x);
            *(u32*)&Bs[(cg * 8 + 1) * 40 + 2 * kp] = pack2bf(a0.y, c0.y);
            *(u32*)&Bs[(cg * 8 + 2) * 40 + 2 * kp] = pack2bf(a0.z, c0.z);
            *(u32*)&Bs[(cg * 8 + 3) * 40 + 2 * kp] = pack2bf(a0.w, c0.w);
            *(u32*)&Bs[(cg * 8 + 4) * 40 + 2 * kp] = pack2bf(a1.x, c1.x);
            *(u32*)&Bs[(cg * 8 + 5) * 40 + 2 * kp] = pack2bf(a1.y, c1.y);
            *(u32*)&Bs[(cg * 8 + 6) * 40 + 2 * kp] = pack2bf(a1.z, c1.z);
            *(u32*)&Bs[(cg * 8 + 7) * 40 + 2 * kp] = pack2bf(a1.w, c1.w);
        } else {
            const u16* w0p = (const u16*)wpv + (size_t)(k0 + 2 * kp) * CDIM + n0 + cg * 8;
            const u16* w1p = w0p + CDIM;
            uint4 ua = *(const uint4*)w0p;
            uint4 ub = *(const uint4*)w1p;
            *(u32*)&Bs[(cg * 8 + 0) * 40 + 2 * kp] = (ua.x & 0xFFFFu) | (ub.x << 16);
            *(u32*)&Bs[(cg * 8 + 1) * 40 + 2 * kp] = (ua.x >> 16) | (ub.x & 0xFFFF0000u);
            *(u32*)&Bs[(cg * 8 + 2) * 40 + 2 * kp] = (ua.y & 0xFFFFu) | (ub.y << 16);
            *(u32*)&Bs[(cg * 8 + 3) * 40 + 2 * kp] = (ua.y >> 16) | (ub.y & 0xFFFF0000u);
            *(u32*)&Bs[(cg * 8 + 4) * 40 + 2 * kp] = (ua.z & 0xFFFFu) | (ub.z << 16);
            *(u32*)&Bs[(cg * 8 + 5) * 40 + 2 * kp] = (ua.z >> 16) | (ub.z & 0xFFFF0000u);
            *(u32*)&Bs[(cg * 8 + 6) * 40 + 2 * kp] = (ua.w & 0xFFFFu) | (ub.w << 16);
            *(u32*)&Bs[(cg * 8 + 7) * 40 + 2 * kp] = (ua.w >> 16) | (ub.w & 0xFFFF0000u);
        }
        __syncthreads();
        bf16x8 af[4], bfr[4];
#pragma unroll
        for (int m = 0; m < 4; ++m)
            af[m] = *(const bf16x8*)&As[(wm * 64 + m * 16 + lo) * 40 + hi * 8];
#pragma unroll
        for (int n = 0; n < 4; ++n)
            bfr[n] = *(const bf16x8*)&Bs[(wn * 64 + n * 16 + lo) * 40 + hi * 8];
#pragma unroll
        for (int m = 0; m < 4; ++m)
#pragma unroll
            for (int n = 0; n < 4; ++n)
                acc[m][n] = __builtin_amdgcn_mfma_f32_16x16x32_bf16(af[m], bfr[n], acc[m][n], 0, 0, 0);
        __syncthreads();
    }

    float bias[4];
    int col_[4];
#pragma unroll
    for (int n = 0; n < 4; ++n) {
        col_[n] = n0 + wn * 64 + n * 16 + lo;
        bias[n] = FP32 ? ((const float*)bpv)[col_[n]] : bf2f(((const u16*)bpv)[col_[n]]);
    }
#pragma unroll
    for (int m = 0; m < 4; ++m) {
#pragma unroll
        for (int j = 0; j < 4; ++j) {
            int rr = mb * 128 + wm * 64 + m * 16 + hi * 4 + j;
            int wi2 = rr / 196, tk = rr - wi2 * 196;
            int b2 = wi2 >> 4, wrem2 = wi2 & 15, wr2 = wrem2 >> 2, wc2 = wrem2 & 3;
            int tr2 = tk / 14, tc2 = tk - tr2 * 14;
            size_t obase = ((size_t)b2 * 3136 +
                            (size_t)((wr2 * 14 + tr2) * 56 + wc2 * 14 + tc2)) * CDIM;
#pragma unroll
            for (int n = 0; n < 4; ++n) {
                size_t off = obase + col_[n];
                if (FP32) {
                    ((float*)outv)[off] = acc[m][n][j] + bias[n] + ((const float*)xv)[off];
                } else {
                    ((u16*)outv)[off] =
                        f2bf(acc[m][n][j] + bias[n] + bf2f(((const u16*)xv)[off]));
                }
            }
        }
    }
}

extern "C" void kernel_launch(void* const* d_in, const int* in_sizes, int n_in,
                              void* d_out, int out_size, void* d_ws, size_t ws_size,
                              hipStream_t stream) {
    const void* x      = d_in[0];
    const void* w_qkv  = d_in[1];
    const void* b_qkv  = d_in[2];
    const void* w_proj = d_in[3];
    const void* b_proj = d_in[4];

    const size_t perF   = (size_t)NWIN * NHEAD * NTOK * DHEAD;  // 38,535,168 elems
    const size_t bytesF = perF * sizeof(u16);                   // 77,070,336 B

    if (ws_size >= 3 * bytesF + sizeof(int)) {
        // one-pass layout: [qb][kb][vb/attn-out][flag]
        u16* qbp = (u16*)d_ws;
        u16* kbp = qbp + perF;
        u16* vbp = kbp + perF;
        int* flag = (int*)((char*)d_ws + 3 * bytesF);

        detect_kernel<<<1, 256, 0, stream>>>((const u16*)w_qkv, flag);

        qkvmm_kernel<false><<<392 * 12, 256, 0, stream>>>(x, w_qkv, b_qkv, flag, qbp, kbp, vbp, 0, 392);
        qkvmm_kernel<true ><<<392 * 12, 256, 0, stream>>>(x, w_qkv, b_qkv, flag, qbp, kbp, vbp, 0, 392);

        attn_kernel<false><<<NWIN * NHEAD, 256, 0, stream>>>(qbp, kbp, vbp, vbp, flag, 0);
        attn_kernel<true ><<<NWIN * NHEAD, 256, 0, stream>>>(qbp, kbp, vbp, vbp, flag, 0);

        projmm_kernel<false><<<2352, 256, 0, stream>>>(vbp, w_proj, b_proj, x, flag, d_out);
        projmm_kernel<true ><<<2352, 256, 0, stream>>>(vbp, w_proj, b_proj, x, flag, d_out);
    } else {
        // chunked layout: [ao full 77MB][qb_c][kb_c][vb_c][flag], 4 chunks of 64 windows
        const int    NWC  = 64;
        const size_t perC = (size_t)NWC * NHEAD * NTOK * DHEAD; // 9,633,792 elems
        u16* ao  = (u16*)d_ws;
        u16* qbp = ao + perF;
        u16* kbp = qbp + perC;
        u16* vbp = kbp + perC;
        int* flag = (int*)((char*)d_ws + bytesF + 3 * perC * sizeof(u16));

        detect_kernel<<<1, 256, 0, stream>>>((const u16*)w_qkv, flag);

        for (int c = 0; c < 4; ++c) {
            int win0 = c * NWC;
            qkvmm_kernel<false><<<98 * 12, 256, 0, stream>>>(x, w_qkv, b_qkv, flag, qbp, kbp, vbp, win0, 98);
            qkvmm_kernel<true ><<<98 * 12, 256, 0, stream>>>(x, w_qkv, b_qkv, flag, qbp, kbp, vbp, win0, 98);
            attn_kernel<false><<<NWC * NHEAD, 256, 0, stream>>>(qbp, kbp, vbp, ao, flag, win0);
            attn_kernel<true ><<<NWC * NHEAD, 256, 0, stream>>>(qbp, kbp, vbp, ao, flag, win0);
        }

        projmm_kernel<false><<<2352, 256, 0, stream>>>(ao, w_proj, b_proj, x, flag, d_out);
        projmm_kernel<true ><<<2352, 256, 0, stream>>>(ao, w_proj, b_proj, x, flag, d_out);
    }
}

// Round 4
// 896.257 us; speedup vs baseline: 15.7814x; 1.0627x over previous
//
#include <hip/hip_runtime.h>

// WindowedMultiHeadAttention. B=16, 56x56 tokens, C=768, 8 heads x d=96,
// 14x14 windows -> 256 windows x 196 tokens.
// Round 6: pre-pass kernels build Wt (w_qkv transposed/rearranged, bf16,
// k-contiguous — exactly the B-fragment layout), Wpt (w_proj transposed) and
// xbf (x pre-rounded to bf16). qkvmm/projmm staging becomes pure uint4
// copies (kills the 8-way bank-conflict scatter + pack2bf VALU). XCD-chunked
// mb-major block swizzle so the 12 nb-tiles sharing an x-tile run adjacent
// on one XCD. attn: + s_setprio around MFMA clusters.
// Workspace tiers (adaptive):
//   A >=313.0 MB: [qb][kb][vb][xbf][Wt][Wpt][flag]  one pass, copy staging
//   B >=235.9 MB: [qb][kb][vb][Wt][Wpt][flag]       one pass, fp32 A-staging
//   C  else     : [ao][qc][kc][vc][Wt][Wpt][flag]   4 window-chunks

#define NWIN 256
#define NTOK 196
#define CDIM 768
#define NHEAD 8
#define DHEAD 96
#define C3 2304

typedef unsigned short u16;
typedef unsigned int u32;
typedef __attribute__((ext_vector_type(8))) short bf16x8;  // 8 bf16 (4 VGPRs)
typedef __attribute__((ext_vector_type(4))) float f32x4;   // MFMA C/D frag

__device__ __forceinline__ float bf2f(u16 u) {
    union { u32 i; float f; } cv;
    cv.i = ((u32)u) << 16;
    return cv.f;
}
__device__ __forceinline__ u16 f2bf(float f) {
    union { float f; u32 i; } cv;
    cv.f = f;
    u32 x = cv.i;
    x = x + 0x7FFFu + ((x >> 16) & 1u);   // RNE
    return (u16)(x >> 16);
}
__device__ __forceinline__ u32 pack2bf(float a, float b) {
    return (u32)f2bf(a) | ((u32)f2bf(b) << 16);
}

// ------------------------------------------------------------- dtype detect
// flag=1 -> inputs are fp32; flag=0 -> bf16.
__global__ void detect_kernel(const u16* __restrict__ w, int* __restrict__ flag) {
    __shared__ int any;
    int t = threadIdx.x;
    if (t == 0) any = 0;
    __syncthreads();
    int hit = 0;
    for (int i = 0; i < 16; ++i) {
        u16 u = w[t * 16 + i];
        int e = (u >> 7) & 0xFF;
        if (e >= 140) hit = 1;    // |val| >= 2^13: impossible for bf16 weights
    }
    if (hit) atomicOr(&any, 1);
    __syncthreads();
    if (t == 0) flag[0] = any;
}

// ------------------------------------------------------- pre-pass: x -> bf16
__global__ __launch_bounds__(256) void convx_kernel(
    const float* __restrict__ x, const int* __restrict__ flag, u16* __restrict__ xb)
{
    if (flag[0] != 1) return;
    size_t gid = (size_t)blockIdx.x * 256 + threadIdx.x;
    const float4* s = (const float4*)(x + gid * 8);
    float4 a = s[0], b = s[1];
    uint4 o;
    o.x = pack2bf(a.x, a.y); o.y = pack2bf(a.z, a.w);
    o.z = pack2bf(b.x, b.y); o.w = pack2bf(b.z, b.w);
    *(uint4*)(xb + gid * 8) = o;
}

// ---------------------- pre-pass: Wt[which*768+d][k] = Wqkv[k][h*288+3*dh+which]
template<bool FP32>
__global__ __launch_bounds__(256) void bwt_kernel(
    const void* __restrict__ w, const int* __restrict__ flag, u16* __restrict__ wt)
{
    if (flag[0] != (FP32 ? 1 : 0)) return;
    int gid = blockIdx.x * 256 + threadIdx.x;     // 2304*96 = 221,184
    int r = gid / 96, kg = gid - r * 96;
    int k0 = kg * 8;
    int which = r / 768, d = r - which * 768;
    int h = d / 96, dh = d - h * 96;
    int src = h * 288 + 3 * dh + which;
    u16 o[8];
#pragma unroll
    for (int j = 0; j < 8; ++j) {
        o[j] = FP32 ? f2bf(((const float*)w)[(size_t)(k0 + j) * C3 + src])
                    : ((const u16*)w)[(size_t)(k0 + j) * C3 + src];
    }
    uint4 v;
    v.x = (u32)o[0] | ((u32)o[1] << 16);
    v.y = (u32)o[2] | ((u32)o[3] << 16);
    v.z = (u32)o[4] | ((u32)o[5] << 16);
    v.w = (u32)o[6] | ((u32)o[7] << 16);
    *(uint4*)&wt[(size_t)r * 768 + k0] = v;
}

// -------------------------------- pre-pass: Wpt[c][k] = Wproj[k][c], bf16
template<bool FP32>
__global__ __launch_bounds__(256) void bwpt_kernel(
    const void* __restrict__ w, const int* __restrict__ flag, u16* __restrict__ wpt)
{
    if (flag[0] != (FP32 ? 1 : 0)) return;
    int gid = blockIdx.x * 256 + threadIdx.x;     // 768*96 = 73,728
    int r = gid / 96, kg = gid - r * 96;
    int k0 = kg * 8;
    u16 o[8];
#pragma unroll
    for (int j = 0; j < 8; ++j) {
        o[j] = FP32 ? f2bf(((const float*)w)[(size_t)(k0 + j) * CDIM + r])
                    : ((const u16*)w)[(size_t)(k0 + j) * CDIM + r];
    }
    uint4 v;
    v.x = (u32)o[0] | ((u32)o[1] << 16);
    v.y = (u32)o[2] | ((u32)o[3] << 16);
    v.z = (u32)o[4] | ((u32)o[5] << 16);
    v.w = (u32)o[6] | ((u32)o[7] << 16);
    *(uint4*)&wpt[(size_t)r * 768 + k0] = v;
}

// --------------------------------------------------------- K1: QKV GEMM, MFMA
// C(rows x 2304) = Xwin(rows x 768) @ Wqkv. Block tile 128 x 192
// (192 cols = {q,k,v} x 64 d-values). B staged from pre-transposed Wt
// (pure uint4 copy). XCD-chunked mb-major swizzle: 12 nb-blocks sharing an
// x-tile run adjacent on one XCD. XBF: xsrc already bf16 (copy staging);
// else xsrc fp32 (convert in staging, tiers B/C).
template<bool XBF>
__global__ __launch_bounds__(256, 2) void qkvmm_kernel(
    const void* __restrict__ xsrc, const void* __restrict__ bvv,
    const u16* __restrict__ wt, const int* __restrict__ flag, int expect,
    u16* __restrict__ qb, u16* __restrict__ kb, u16* __restrict__ vb,
    int win0, int mtiles)
{
    if (flag[0] != expect) return;
    __shared__ u16 As[128 * 40];   // A[row][k], 40-pad (80B stride)
    __shared__ u16 Bs[192 * 40];   // Bt[c][k]

    int t = threadIdx.x;
    int cpx = (mtiles * 12) >> 3;                // blocks per XCD (divisible)
    int g = blockIdx.x;
    int wid = (g & 7) * cpx + (g >> 3);          // bijective XCD-chunk swizzle
    int mb = wid / 12;
    int nb = wid - mb * 12;
    int nb64 = nb * 64;

    // ---- A staging coords: thread = (row, 16-col half) ----
    int arow = t >> 1, ahalf = t & 1;
    int rloc = mb * 128 + arow;
    int wiL = rloc / 196, tok = rloc - wiL * 196;
    int wiA = win0 + wiL;
    int b_ = wiA >> 4, wrem = wiA & 15, wr = wrem >> 2, wc = wrem & 3;
    int tr = tok / 14, tc = tok - tr * 14;
    size_t xrow = ((size_t)b_ * 3136 + (size_t)((wr * 14 + tr) * 56 + wc * 14 + tc)) * CDIM;

    f32x4 acc[4][6];
#pragma unroll
    for (int m = 0; m < 4; ++m)
#pragma unroll
        for (int n = 0; n < 6; ++n)
            acc[m][n] = (f32x4){0.f, 0.f, 0.f, 0.f};

    int lane = t & 63, wvid = t >> 6;
    int wm = wvid >> 1, wn = wvid & 1;
    int lo = lane & 15, hi = lane >> 4;

#pragma unroll 1
    for (int kk = 0; kk < 24; ++kk) {
        int k0 = kk * 32;
        // ---- stage A ----
        {
            uint4* dst = (uint4*)&As[arow * 40 + ahalf * 16];
            if (XBF) {
                const uint4* xp = (const uint4*)((const u16*)xsrc + xrow + k0 + ahalf * 16);
                dst[0] = xp[0];
                dst[1] = xp[1];
            } else {
                const float4* xp = (const float4*)((const float*)xsrc + xrow + k0 + ahalf * 16);
                float4 f0 = xp[0], f1 = xp[1], f2 = xp[2], f3 = xp[3];
                uint4 d0, d1;
                d0.x = pack2bf(f0.x, f0.y); d0.y = pack2bf(f0.z, f0.w);
                d0.z = pack2bf(f1.x, f1.y); d0.w = pack2bf(f1.z, f1.w);
                d1.x = pack2bf(f2.x, f2.y); d1.y = pack2bf(f2.z, f2.w);
                d1.z = pack2bf(f3.x, f3.y); d1.w = pack2bf(f3.z, f3.w);
                dst[0] = d0; dst[1] = d1;
            }
        }
        // ---- stage B: uint4 copy from Wt (192 rows x 2 halves = 384 units) ----
        {
            int c = t >> 1, half = t & 1;
            int wrow = (c >> 6) * 768 + nb64 + (c & 63);
            const uint4* sp = (const uint4*)(wt + (size_t)wrow * 768 + k0 + half * 16);
            uint4* dp = (uint4*)&Bs[c * 40 + half * 16];
            dp[0] = sp[0]; dp[1] = sp[1];
        }
        if (t < 128) {
            int i = t + 256;
            int c = i >> 1, half = i & 1;
            int wrow = (c >> 6) * 768 + nb64 + (c & 63);
            const uint4* sp = (const uint4*)(wt + (size_t)wrow * 768 + k0 + half * 16);
            uint4* dp = (uint4*)&Bs[c * 40 + half * 16];
            dp[0] = sp[0]; dp[1] = sp[1];
        }
        __syncthreads();
        // ---- fragments + MFMA ----
        bf16x8 af[4], bfr[6];
#pragma unroll
        for (int m = 0; m < 4; ++m)
            af[m] = *(const bf16x8*)&As[(wm * 64 + m * 16 + lo) * 40 + hi * 8];
#pragma unroll
        for (int n = 0; n < 6; ++n)
            bfr[n] = *(const bf16x8*)&Bs[(wn * 96 + n * 16 + lo) * 40 + hi * 8];
        __builtin_amdgcn_s_setprio(1);
#pragma unroll
        for (int m = 0; m < 4; ++m)
#pragma unroll
            for (int n = 0; n < 6; ++n)
                acc[m][n] = __builtin_amdgcn_mfma_f32_16x16x32_bf16(af[m], bfr[n], acc[m][n], 0, 0, 0);
        __builtin_amdgcn_s_setprio(0);
        __syncthreads();
    }

    // ---- store (+bias). D frag: col = lo, row = hi*4 + j ----
    float bias[6];
    int h2_[6], dh2_[6], wh_[6];
#pragma unroll
    for (int n = 0; n < 6; ++n) {
        int c = wn * 96 + n * 16 + lo;
        wh_[n] = c >> 6;                       // 0=q, 1=k, 2=v
        int d_abs = nb64 + (c & 63);
        h2_[n] = d_abs / 96; dh2_[n] = d_abs - h2_[n] * 96;
        int bcol = h2_[n] * 288 + 3 * dh2_[n] + wh_[n];
        bias[n] = expect ? ((const float*)bvv)[bcol] : bf2f(((const u16*)bvv)[bcol]);
    }
#pragma unroll
    for (int m = 0; m < 4; ++m) {
#pragma unroll
        for (int j = 0; j < 4; ++j) {
            int rr = mb * 128 + wm * 64 + m * 16 + hi * 4 + j;   // chunk-relative
            int wir = rr / 196, tk = rr - wir * 196;
            size_t rowpart = (size_t)wir * (8 * 196) + (size_t)tk;
#pragma unroll
            for (int n = 0; n < 6; ++n) {
                u16* ob = wh_[n] == 0 ? qb : (wh_[n] == 1 ? kb : vb);
                ob[(rowpart + (size_t)h2_[n] * 196) * 96 + dh2_[n]] =
                    f2bf(acc[m][n][j] + bias[n]);
            }
        }
    }
}

// ------------------------------------------------------ K2: attention (slim)
// block = (wi_rel, head), 4 waves; wave owns q-tiles {w, w+4, w+8, w+12} < 13.
// Q/K frags direct from global; LDS: V^T + P only. Dtype-independent.
__global__ __launch_bounds__(256, 2) void attn_kernel(
    const u16* __restrict__ qbp, const u16* __restrict__ kbp,
    const u16* __restrict__ vbp, u16* __restrict__ ao, int win0)
{
    __shared__ u16 Vt[96 * 232];          // 44,544 B  V^T[d][key], keys 196-223 zero
    __shared__ u16 Pl[4 * 16 * 232];      // 29,696 B  per-wave P[q][key]

    int bh = blockIdx.x;                  // wi_rel*8 + h
    int t  = threadIdx.x;
    int lane = t & 63, w = t >> 6;
    int lo = lane & 15, hi = lane >> 4;

    const u16* qbase = qbp + (size_t)bh * (NTOK * DHEAD);
    const u16* kbase = kbp + (size_t)bh * (NTOK * DHEAD);
    const u16* vbase = vbp + (size_t)bh * (NTOK * DHEAD);
    u16* obase = ao + ((size_t)bh + (size_t)win0 * 8) * (NTOK * DHEAD);

    // ---- stage V^T (tp varies fastest -> consecutive banks); zero pads ----
#pragma unroll 1
    for (int i = t; i < 112 * 12; i += 256) {
        int tp = i % 112, dgv = i / 112;
        int dbase = dgv * 8, cpos = 2 * tp;
        uint4 a = {0, 0, 0, 0}, bq = {0, 0, 0, 0};
        if (tp < 98) {
            const u16* v0 = vbase + (size_t)(2 * tp) * 96 + dbase;
            a  = *(const uint4*)v0;
            bq = *(const uint4*)(v0 + 96);
        }
        *(u32*)&Vt[(dbase + 0) * 232 + cpos] = (a.x & 0xFFFFu) | (bq.x << 16);
        *(u32*)&Vt[(dbase + 1) * 232 + cpos] = (a.x >> 16) | (bq.x & 0xFFFF0000u);
        *(u32*)&Vt[(dbase + 2) * 232 + cpos] = (a.y & 0xFFFFu) | (bq.y << 16);
        *(u32*)&Vt[(dbase + 3) * 232 + cpos] = (a.y >> 16) | (bq.y & 0xFFFF0000u);
        *(u32*)&Vt[(dbase + 4) * 232 + cpos] = (a.z & 0xFFFFu) | (bq.z << 16);
        *(u32*)&Vt[(dbase + 5) * 232 + cpos] = (a.z >> 16) | (bq.z & 0xFFFF0000u);
        *(u32*)&Vt[(dbase + 6) * 232 + cpos] = (a.w & 0xFFFFu) | (bq.w << 16);
        *(u32*)&Vt[(dbase + 7) * 232 + cpos] = (a.w >> 16) | (bq.w & 0xFFFF0000u);
    }
    __syncthreads();

    u16* pw = Pl + w * (16 * 232);
#pragma unroll 1
    for (int i = 0; i < 4; ++i) {
        int qt = w + 4 * i;
        if (qt >= 13) break;
        // Q B-frags direct from global (rows >=196 clamped; outputs masked)
        int qrow = qt * 16 + lo; if (qrow > 195) qrow = 195;
        bf16x8 qf[3];
#pragma unroll
        for (int ks = 0; ks < 3; ++ks)
            qf[ks] = *(const bf16x8*)(qbase + (size_t)qrow * 96 + ks * 32 + hi * 8);
        // S^T = K @ Q^T : D[key][q]; K A-frags direct from global
        f32x4 sc[13];
#pragma unroll
        for (int kt = 0; kt < 13; ++kt) sc[kt] = (f32x4){0.f, 0.f, 0.f, 0.f};
        __builtin_amdgcn_s_setprio(1);
#pragma unroll
        for (int kt = 0; kt < 13; ++kt) {
            int krow = kt * 16 + lo; if (krow > 195) krow = 195;
            const u16* kr = kbase + (size_t)krow * 96;
#pragma unroll
            for (int ks = 0; ks < 3; ++ks) {
                bf16x8 kf = *(const bf16x8*)(kr + ks * 32 + hi * 8);
                sc[kt] = __builtin_amdgcn_mfma_f32_16x16x32_bf16(kf, qf[ks], sc[kt], 0, 0, 0);
            }
        }
        __builtin_amdgcn_s_setprio(0);
        // softmax for query q = qt*16 + lo (this lane's column)
        float p[52];
        float mx = -1e30f;
#pragma unroll
        for (int kt = 0; kt < 13; ++kt)
#pragma unroll
            for (int j = 0; j < 4; ++j) {
                float e = sc[kt][j];
                if (kt == 12 && hi != 0) e = -1e30f;   // keys >= 196
                p[kt * 4 + j] = e;
                mx = fmaxf(mx, e);
            }
        mx = fmaxf(mx, __shfl_xor(mx, 16));
        mx = fmaxf(mx, __shfl_xor(mx, 32));
        float l = 0.f;
#pragma unroll
        for (int z = 0; z < 52; ++z) {
            float e = __expf(p[z] - mx);
            p[z] = e;
            l += e;
        }
        l += __shfl_xor(l, 16);
        l += __shfl_xor(l, 32);
        float rs = 1.0f / (l * 27.712812921102035f);   // softmax, THEN /sqrt(768)
        // write P (pre-scaled) to per-wave LDS: P[q=lo][key]
#pragma unroll
        for (int kt = 0; kt < 13; ++kt) {
            *(u32*)&pw[lo * 232 + kt * 16 + hi * 4]     = pack2bf(p[kt * 4 + 0] * rs, p[kt * 4 + 1] * rs);
            *(u32*)&pw[lo * 232 + kt * 16 + hi * 4 + 2] = pack2bf(p[kt * 4 + 2] * rs, p[kt * 4 + 3] * rs);
        }
        *(u32*)&pw[lo * 232 + 208 + hi * 4]     = 0;   // zero keys 208..223
        *(u32*)&pw[lo * 232 + 208 + hi * 4 + 2] = 0;
        asm volatile("s_waitcnt lgkmcnt(0)" ::: "memory");
        __builtin_amdgcn_sched_barrier(0);
        // PV: O[q][d] — A = P, B = V^T
        f32x4 oa[6];
#pragma unroll
        for (int n = 0; n < 6; ++n) oa[n] = (f32x4){0.f, 0.f, 0.f, 0.f};
        __builtin_amdgcn_s_setprio(1);
#pragma unroll
        for (int ks = 0; ks < 7; ++ks) {
            bf16x8 pf = *(const bf16x8*)&pw[lo * 232 + ks * 32 + hi * 8];
#pragma unroll
            for (int n = 0; n < 6; ++n) {
                bf16x8 vf = *(const bf16x8*)&Vt[(n * 16 + lo) * 232 + ks * 32 + hi * 8];
                oa[n] = __builtin_amdgcn_mfma_f32_16x16x32_bf16(pf, vf, oa[n], 0, 0, 0);
            }
        }
        __builtin_amdgcn_s_setprio(0);
        // store O (absolute-indexed attn-out)
#pragma unroll
        for (int n = 0; n < 6; ++n)
#pragma unroll
            for (int j = 0; j < 4; ++j) {
                int q = qt * 16 + hi * 4 + j;
                if (q < NTOK)
                    obase[(size_t)q * 96 + n * 16 + lo] = f2bf(oa[n][j]);
            }
    }
}

// ---------------------------------------------- K3: proj GEMM, MFMA + epilogue
template<bool FP32>
__global__ __launch_bounds__(256, 2) void projmm_kernel(
    const u16* __restrict__ ao,            // (256*8,196,96) attn out
    const u16* __restrict__ wpt,           // pre-transposed Wproj [c][k] bf16
    const void* __restrict__ bpv,
    const void* __restrict__ xv, const int* __restrict__ flag,
    void* __restrict__ outv)
{
    if (flag[0] != (FP32 ? 1 : 0)) return;
    __shared__ u16 As[128 * 40];
    __shared__ u16 Bs[128 * 40];

    int t = threadIdx.x;
    int g = blockIdx.x;                    // 2352 = 8 * 294
    int wid = (g & 7) * 294 + (g >> 3);
    int mb = wid / 6;
    int nb = wid - mb * 6;
    int n0 = nb * 128;

    int arow = t >> 1, ahalf = t & 1;
    int r = mb * 128 + arow;
    int wi = r / 196, tok = r - wi * 196;
    size_t aobase = (size_t)(wi * 8) * 196 + (size_t)tok;

    f32x4 acc[4][4];
#pragma unroll
    for (int m = 0; m < 4; ++m)
#pragma unroll
        for (int n = 0; n < 4; ++n)
            acc[m][n] = (f32x4){0.f, 0.f, 0.f, 0.f};

    int lane = t & 63, wvid = t >> 6;
    int wm = wvid >> 1, wn = wvid & 1;
    int lo = lane & 15, hi = lane >> 4;

#pragma unroll 1
    for (int kk = 0; kk < 24; ++kk) {
        int k0 = kk * 32;
        // ---- stage A from ao (bf16); 16-chunks never cross heads ----
        {
            int kabs = k0 + ahalf * 16;
            int h = kabs / 96, dd = kabs - h * 96;
            const uint4* ap = (const uint4*)(ao + (aobase + (size_t)h * 196) * 96 + dd);
            uint4* dst = (uint4*)&As[arow * 40 + ahalf * 16];
            dst[0] = ap[0]; dst[1] = ap[1];
        }
        // ---- stage B: uint4 copy from Wpt (128 rows x 2 halves = 256 units) ----
        {
            int c = t >> 1, half = t & 1;
            const uint4* sp = (const uint4*)(wpt + (size_t)(n0 + c) * 768 + k0 + half * 16);
            uint4* dp = (uint4*)&Bs[c * 40 + half * 16];
            dp[0] = sp[0]; dp[1] = sp[1];
        }
        __syncthreads();
        bf16x8 af[4], bfr[4];
#pragma unroll
        for (int m = 0; m < 4; ++m)
            af[m] = *(const bf16x8*)&As[(wm * 64 + m * 16 + lo) * 40 + hi * 8];
#pragma unroll
        for (int n = 0; n < 4; ++n)
            bfr[n] = *(const bf16x8*)&Bs[(wn * 64 + n * 16 + lo) * 40 + hi * 8];
        __builtin_amdgcn_s_setprio(1);
#pragma unroll
        for (int m = 0; m < 4; ++m)
#pragma unroll
            for (int n = 0; n < 4; ++n)
                acc[m][n] = __builtin_amdgcn_mfma_f32_16x16x32_bf16(af[m], bfr[n], acc[m][n], 0, 0, 0);
        __builtin_amdgcn_s_setprio(0);
        __syncthreads();
    }

    float bias[4];
    int col_[4];
#pragma unroll
    for (int n = 0; n < 4; ++n) {
        col_[n] = n0 + wn * 64 + n * 16 + lo;
        bias[n] = FP32 ? ((const float*)bpv)[col_[n]] : bf2f(((const u16*)bpv)[col_[n]]);
    }
#pragma unroll
    for (int m = 0; m < 4; ++m) {
#pragma unroll
        for (int j = 0; j < 4; ++j) {
            int rr = mb * 128 + wm * 64 + m * 16 + hi * 4 + j;
            int wi2 = rr / 196, tk = rr - wi2 * 196;
            int b2 = wi2 >> 4, wrem2 = wi2 & 15, wr2 = wrem2 >> 2, wc2 = wrem2 & 3;
            int tr2 = tk / 14, tc2 = tk - tr2 * 14;
            size_t obase = ((size_t)b2 * 3136 +
                            (size_t)((wr2 * 14 + tr2) * 56 + wc2 * 14 + tc2)) * CDIM;
#pragma unroll
            for (int n = 0; n < 4; ++n) {
                size_t off = obase + col_[n];
                if (FP32) {
                    ((float*)outv)[off] = acc[m][n][j] + bias[n] + ((const float*)xv)[off];
                } else {
                    ((u16*)outv)[off] =
                        f2bf(acc[m][n][j] + bias[n] + bf2f(((const u16*)xv)[off]));
                }
            }
        }
    }
}

extern "C" void kernel_launch(void* const* d_in, const int* in_sizes, int n_in,
                              void* d_out, int out_size, void* d_ws, size_t ws_size,
                              hipStream_t stream) {
    const void* x      = d_in[0];
    const void* w_qkv  = d_in[1];
    const void* b_qkv  = d_in[2];
    const void* w_proj = d_in[3];
    const void* b_proj = d_in[4];

    const size_t perF  = (size_t)NWIN * NHEAD * NTOK * DHEAD;  // 38,535,168 elems
    const size_t wtE   = (size_t)C3 * CDIM;                    // 1,769,472 elems
    const size_t wptE  = (size_t)CDIM * CDIM;                  //   589,824 elems
    const size_t needA = (4 * perF + wtE + wptE) * 2 + 4;      // 312,999,940 B
    const size_t needB = (3 * perF + wtE + wptE) * 2 + 4;      // 235,929,604 B

    u16* base = (u16*)d_ws;

    if (ws_size >= needA) {
        // tier A: [qb][kb][vb][xbf][Wt][Wpt][flag]
        u16* qbp = base;
        u16* kbp = qbp + perF;
        u16* vbp = kbp + perF;
        u16* xbf = vbp + perF;
        u16* wt  = xbf + perF;
        u16* wpt = wt + wtE;
        int* flag = (int*)(wpt + wptE);

        detect_kernel<<<1, 256, 0, stream>>>((const u16*)w_qkv, flag);
        convx_kernel<<<18816, 256, 0, stream>>>((const float*)x, flag, xbf);
        bwt_kernel<false><<<864, 256, 0, stream>>>(w_qkv, flag, wt);
        bwt_kernel<true ><<<864, 256, 0, stream>>>(w_qkv, flag, wt);
        bwpt_kernel<false><<<288, 256, 0, stream>>>(w_proj, flag, wpt);
        bwpt_kernel<true ><<<288, 256, 0, stream>>>(w_proj, flag, wpt);

        qkvmm_kernel<true><<<392 * 12, 256, 0, stream>>>(x,   b_qkv, wt, flag, 0, qbp, kbp, vbp, 0, 392);
        qkvmm_kernel<true><<<392 * 12, 256, 0, stream>>>(xbf, b_qkv, wt, flag, 1, qbp, kbp, vbp, 0, 392);

        attn_kernel<<<NWIN * NHEAD, 256, 0, stream>>>(qbp, kbp, vbp, vbp, 0);

        projmm_kernel<false><<<2352, 256, 0, stream>>>(vbp, wpt, b_proj, x, flag, d_out);
        projmm_kernel<true ><<<2352, 256, 0, stream>>>(vbp, wpt, b_proj, x, flag, d_out);
    } else if (ws_size >= needB) {
        // tier B: [qb][kb][vb][Wt][Wpt][flag] — fp32 A-staging in qkvmm
        u16* qbp = base;
        u16* kbp = qbp + perF;
        u16* vbp = kbp + perF;
        u16* wt  = vbp + perF;
        u16* wpt = wt + wtE;
        int* flag = (int*)(wpt + wptE);

        detect_kernel<<<1, 256, 0, stream>>>((const u16*)w_qkv, flag);
        bwt_kernel<false><<<864, 256, 0, stream>>>(w_qkv, flag, wt);
        bwt_kernel<true ><<<864, 256, 0, stream>>>(w_qkv, flag, wt);
        bwpt_kernel<false><<<288, 256, 0, stream>>>(w_proj, flag, wpt);
        bwpt_kernel<true ><<<288, 256, 0, stream>>>(w_proj, flag, wpt);

        qkvmm_kernel<true ><<<392 * 12, 256, 0, stream>>>(x, b_qkv, wt, flag, 0, qbp, kbp, vbp, 0, 392);
        qkvmm_kernel<false><<<392 * 12, 256, 0, stream>>>(x, b_qkv, wt, flag, 1, qbp, kbp, vbp, 0, 392);

        attn_kernel<<<NWIN * NHEAD, 256, 0, stream>>>(qbp, kbp, vbp, vbp, 0);

        projmm_kernel<false><<<2352, 256, 0, stream>>>(vbp, wpt, b_proj, x, flag, d_out);
        projmm_kernel<true ><<<2352, 256, 0, stream>>>(vbp, wpt, b_proj, x, flag, d_out);
    } else {
        // tier C: [ao][qc][kc][vc][Wt][Wpt][flag], 4 chunks of 64 windows
        const int    NWC  = 64;
        const size_t perC = (size_t)NWC * NHEAD * NTOK * DHEAD; // 9,633,792 elems
        u16* ao  = base;
        u16* qbp = ao + perF;
        u16* kbp = qbp + perC;
        u16* vbp = kbp + perC;
        u16* wt  = vbp + perC;
        u16* wpt = wt + wtE;
        int* flag = (int*)(wpt + wptE);

        detect_kernel<<<1, 256, 0, stream>>>((const u16*)w_qkv, flag);
        bwt_kernel<false><<<864, 256, 0, stream>>>(w_qkv, flag, wt);
        bwt_kernel<true ><<<864, 256, 0, stream>>>(w_qkv, flag, wt);
        bwpt_kernel<false><<<288, 256, 0, stream>>>(w_proj, flag, wpt);
        bwpt_kernel<true ><<<288, 256, 0, stream>>>(w_proj, flag, wpt);

        for (int c = 0; c < 4; ++c) {
            int win0 = c * NWC;
            qkvmm_kernel<true ><<<98 * 12, 256, 0, stream>>>(x, b_qkv, wt, flag, 0, qbp, kbp, vbp, win0, 98);
            qkvmm_kernel<false><<<98 * 12, 256, 0, stream>>>(x, b_qkv, wt, flag, 1, qbp, kbp, vbp, win0, 98);
            attn_kernel<<<NWC * NHEAD, 256, 0, stream>>>(qbp, kbp, vbp, ao, win0);
        }

        projmm_kernel<false><<<2352, 256, 0, stream>>>(ao, wpt, b_proj, x, flag, d_out);
        projmm_kernel<true ><<<2352, 256, 0, stream>>>(ao, wpt, b_proj, x, flag, d_out);
    }
}